// Round 1
// baseline (4841.800 us; speedup 1.0000x reference)
//
#include <hip/hip_runtime.h>
#include <hip/hip_bf16.h>
#include <cstdint>

// Problem constants
#define BB 4
#define SS 5440
#define DD 256
#define NHH 8
#define HDD 32
#define NLVV 4
#define NPP 4
#define DFFF 1024
#define NL 6
#define TT (BB*SS)          // 21760 tokens
#define TD ((size_t)TT*DD)  // 5,570,560

// Level tables: starts {0,4096,5120,5376}, W=H {64,32,16,8}

// ---------------------------------------------------------------------------
// Preprocess: build cur = concat(src_l flattened, transposed) and
// pos = concat(pos_l) + level_embed[l]
__global__ __launch_bounds__(256) void prep_kernel(
    const float* __restrict__ s0, const float* __restrict__ p0,
    const float* __restrict__ s1, const float* __restrict__ p1,
    const float* __restrict__ s2, const float* __restrict__ p2,
    const float* __restrict__ s3, const float* __restrict__ p3,
    const float* __restrict__ lev,
    float* __restrict__ cur, float* __restrict__ pos)
{
  size_t idx = (size_t)blockIdx.x * 256 + threadIdx.x;   // over B*S*D
  int d = (int)(idx & 255);
  size_t bs = idx >> 8;
  int b = (int)(bs / SS);
  int s = (int)(bs % SS);
  int l, start, HW;
  const float* sp; const float* pp;
  if (s < 4096)      { l = 0; start = 0;    HW = 4096; sp = s0; pp = p0; }
  else if (s < 5120) { l = 1; start = 4096; HW = 1024; sp = s1; pp = p1; }
  else if (s < 5376) { l = 2; start = 5120; HW = 256;  sp = s2; pp = p2; }
  else               { l = 3; start = 5376; HW = 64;   sp = s3; pp = p3; }
  int p = s - start;
  size_t si = ((size_t)b * DD + d) * HW + p;
  cur[idx] = sp[si];
  pos[idx] = pp[si] + lev[l * DD + d];
}

// ---------------------------------------------------------------------------
// Elementwise add (q = cur + pos), float4
__global__ __launch_bounds__(256) void add_kernel(
    const float* __restrict__ a, const float* __restrict__ b,
    float* __restrict__ o, int n4)
{
  int i = blockIdx.x * 256 + threadIdx.x;
  if (i < n4) {
    float4 x = reinterpret_cast<const float4*>(a)[i];
    float4 y = reinterpret_cast<const float4*>(b)[i];
    float4 z; z.x = x.x + y.x; z.y = x.y + y.y; z.z = x.z + y.z; z.w = x.w + y.w;
    reinterpret_cast<float4*>(o)[i] = z;
  }
}

// ---------------------------------------------------------------------------
// Generic f32 GEMM: C[M,N] = A[M,K] @ W[K,N] + bias[N], optional relu.
// 64x64 tile, 256 threads, 4x4 microtile, K-step 16. M%64==0, N%64==0, K%16==0.
__global__ __launch_bounds__(256) void gemm64(
    const float* __restrict__ A, const float* __restrict__ W,
    const float* __restrict__ bias, float* __restrict__ C,
    int M, int N, int K, int relu)
{
  __shared__ float As[16][68];
  __shared__ float Ws[16][68];
  int tid = threadIdx.x;
  int m0 = blockIdx.x * 64;
  int n0 = blockIdx.y * 64;
  int ty = tid >> 4, tx = tid & 15;
  float acc[4][4] = {};
  for (int k0 = 0; k0 < K; k0 += 16) {
    { // stage A: 64 rows x 16 k, float4 per thread
      int r = tid >> 2;
      int kk = (tid & 3) * 4;
      float4 v = *reinterpret_cast<const float4*>(A + (size_t)(m0 + r) * K + k0 + kk);
      As[kk + 0][r] = v.x; As[kk + 1][r] = v.y; As[kk + 2][r] = v.z; As[kk + 3][r] = v.w;
    }
    { // stage W: 16 rows x 64 cols
      int kk = tid >> 6;      // 0..3
      int c  = tid & 63;
      #pragma unroll
      for (int u = 0; u < 4; ++u)
        Ws[kk + u * 4][c] = W[(size_t)(k0 + kk + u * 4) * N + n0 + c];
    }
    __syncthreads();
    #pragma unroll
    for (int kk = 0; kk < 16; ++kk) {
      float4 a = *reinterpret_cast<const float4*>(&As[kk][ty * 4]);
      float4 b = *reinterpret_cast<const float4*>(&Ws[kk][tx * 4]);
      float av[4] = {a.x, a.y, a.z, a.w};
      float bv[4] = {b.x, b.y, b.z, b.w};
      #pragma unroll
      for (int i = 0; i < 4; ++i)
        #pragma unroll
        for (int j = 0; j < 4; ++j)
          acc[i][j] += av[i] * bv[j];
    }
    __syncthreads();
  }
  #pragma unroll
  for (int i = 0; i < 4; ++i) {
    int m = m0 + ty * 4 + i;
    #pragma unroll
    for (int j = 0; j < 4; ++j) {
      int n = n0 + tx * 4 + j;
      float v = acc[i][j] + bias[n];
      if (relu) v = fmaxf(v, 0.f);
      C[(size_t)m * N + n] = v;
    }
  }
}

// ---------------------------------------------------------------------------
// Deformable sampling: per token, softmax attn weights + bilinear gather.
// One block (256 threads) per token.
__global__ __launch_bounds__(256) void sample_kernel(
    const float* __restrict__ val, const float* __restrict__ soff,
    const float* __restrict__ awl, float* __restrict__ att)
{
  __shared__ int   sIdx[128][4];
  __shared__ float sW[128][4];
  int t = blockIdx.x;
  int b = t / SS, s = t % SS;
  int tid = threadIdx.x;

  if (tid < 128) {
    int pt = tid;                 // h*16 + l*4 + p
    int l = (pt >> 2) & 3;
    // token's own reference point
    int st, Wt;
    if (s < 4096)      { st = 0;    Wt = 64; }
    else if (s < 5120) { st = 4096; Wt = 32; }
    else if (s < 5376) { st = 5120; Wt = 16; }
    else               { st = 5376; Wt = 8;  }
    int p = s - st;
    int iy = p / Wt, ix = p % Wt;
    float refx = (ix + 0.5f) / Wt;
    float refy = (iy + 0.5f) / Wt;   // H == W for all levels

    // softmax over the 16 points of this head (contiguous 16-lane groups)
    float logit = awl[(size_t)t * 128 + pt];
    float m = logit;
    for (int off = 1; off < 16; off <<= 1) m = fmaxf(m, __shfl_xor(m, off));
    float e = __expf(logit - m);
    float sum = e;
    for (int off = 1; off < 16; off <<= 1) sum += __shfl_xor(sum, off);
    float wa = e / sum;

    const int LW[4]  = {64, 32, 16, 8};
    const int LST[4] = {0, 4096, 5120, 5376};
    int Wl = LW[l], Hl = Wl, stl = LST[l];

    float ox = soff[(size_t)t * 256 + pt * 2];
    float oy = soff[(size_t)t * 256 + pt * 2 + 1];
    float x = refx * Wl + ox - 0.5f;
    float y = refy * Hl + oy - 0.5f;
    float x0f = floorf(x), y0f = floorf(y);
    int x0 = (int)x0f, y0 = (int)y0f;
    float wx1 = x - x0f, wy1 = y - y0f;
    int vbase = b * SS + stl;
    #pragma unroll
    for (int c = 0; c < 4; ++c) {
      int dx = c & 1, dy = c >> 1;
      int xi = x0 + dx, yi = y0 + dy;
      float wgt = (dx ? wx1 : 1.f - wx1) * (dy ? wy1 : 1.f - wy1);
      bool valid = (xi >= 0) & (xi < Wl) & (yi >= 0) & (yi < Hl);
      int xc = min(max(xi, 0), Wl - 1), yc = min(max(yi, 0), Hl - 1);
      sIdx[pt][c] = vbase + yc * Wl + xc;
      sW[pt][c] = valid ? wgt * wa : 0.f;
    }
  }
  __syncthreads();

  int d = tid;
  int h = d >> 5;
  float acc = 0.f;
  #pragma unroll
  for (int k = 0; k < 16; ++k) {
    int pt = h * 16 + k;
    #pragma unroll
    for (int c = 0; c < 4; ++c) {
      acc += sW[pt][c] * val[(size_t)sIdx[pt][c] * DD + d];
    }
  }
  att[(size_t)t * DD + d] = acc;
}

// ---------------------------------------------------------------------------
// LayerNorm of (a + r): one block per token, 256 threads.
__global__ __launch_bounds__(256) void ln_kernel(
    const float* __restrict__ a, const float* __restrict__ r,
    const float* __restrict__ g, const float* __restrict__ be,
    float* __restrict__ o)
{
  __shared__ float ps[4], ps2[4];
  int t = blockIdx.x, d = threadIdx.x;
  size_t base = (size_t)t * DD;
  float x = a[base + d] + r[base + d];
  float s = x, s2 = x * x;
  #pragma unroll
  for (int off = 1; off < 64; off <<= 1) {
    s  += __shfl_xor(s, off);
    s2 += __shfl_xor(s2, off);
  }
  int w = d >> 6, lane = d & 63;
  if (lane == 0) { ps[w] = s; ps2[w] = s2; }
  __syncthreads();
  if (d == 0) {
    float ta = ps[0] + ps[1] + ps[2] + ps[3];
    float tb = ps2[0] + ps2[1] + ps2[2] + ps2[3];
    ps[0] = ta; ps2[0] = tb;
  }
  __syncthreads();
  float mean = ps[0] * (1.f / DD);
  float var = ps2[0] * (1.f / DD) - mean * mean;
  float y = (x - mean) * rsqrtf(var + 1e-5f) * g[d] + be[d];
  o[base + d] = y;
}

// ---------------------------------------------------------------------------
// Tail: write spatial_shapes + level_start_index (as float values)
__global__ void tail_kernel(float* __restrict__ o) {
  const float v[12] = {64.f, 64.f, 32.f, 32.f, 16.f, 16.f, 8.f, 8.f,
                       0.f, 4096.f, 5120.f, 5376.f};
  int i = threadIdx.x;
  if (i < 12) o[i] = v[i];
}

// ---------------------------------------------------------------------------
extern "C" void kernel_launch(void* const* d_in, const int* in_sizes, int n_in,
                              void* d_out, int out_size, void* d_ws, size_t ws_size,
                              hipStream_t stream)
{
  const float* s0  = (const float*)d_in[0];
  const float* p0  = (const float*)d_in[1];
  const float* s1  = (const float*)d_in[2];
  const float* p1  = (const float*)d_in[3];
  const float* s2  = (const float*)d_in[4];
  const float* p2  = (const float*)d_in[5];
  const float* s3  = (const float*)d_in[6];
  const float* p3  = (const float*)d_in[7];
  const float* lev = (const float*)d_in[8];
  const float* W_so = (const float*)d_in[9];
  const float* b_so = (const float*)d_in[10];
  const float* W_aw = (const float*)d_in[11];
  const float* b_aw = (const float*)d_in[12];
  const float* W_v  = (const float*)d_in[13];
  const float* b_v  = (const float*)d_in[14];
  const float* W_o  = (const float*)d_in[15];
  const float* b_o  = (const float*)d_in[16];
  const float* g1   = (const float*)d_in[17];
  const float* be1  = (const float*)d_in[18];
  const float* W_f1 = (const float*)d_in[19];
  const float* b_f1 = (const float*)d_in[20];
  const float* W_f2 = (const float*)d_in[21];
  const float* b_f2 = (const float*)d_in[22];
  const float* g2   = (const float*)d_in[23];
  const float* be2  = (const float*)d_in[24];

  float* out = (float*)d_out;   // cur lives in d_out's tensor region
  float* ws  = (float*)d_ws;

  float* pos  = ws;                       // TD
  float* q    = ws + TD;                  // TD      (also reused as att)
  float* soff = ws + 2 * TD;              // TD      (also att_o / ffn_out)
  float* aw   = ws + 3 * TD;              // TD/2
  float* val  = ws + 3 * TD + TD / 2;     // TD      (also x post-LN1)
  float* h    = ws + 4 * TD + TD / 2;     // TD      (FFN hidden, 5440x1024 chunk)

  prep_kernel<<<TT, 256, 0, stream>>>(s0, p0, s1, p1, s2, p2, s3, p3, lev, out, pos);

  for (int i = 0; i < NL; ++i) {
    const float* Wso = W_so + (size_t)i * 256 * 256;
    const float* bso = b_so + (size_t)i * 256;
    const float* Waw = W_aw + (size_t)i * 256 * 128;
    const float* baw = b_aw + (size_t)i * 128;
    const float* Wv  = W_v  + (size_t)i * 256 * 256;
    const float* bv  = b_v  + (size_t)i * 256;
    const float* Wo  = W_o  + (size_t)i * 256 * 256;
    const float* bo  = b_o  + (size_t)i * 256;
    const float* Wf1 = W_f1 + (size_t)i * 256 * 1024;
    const float* bf1 = b_f1 + (size_t)i * 1024;
    const float* Wf2 = W_f2 + (size_t)i * 1024 * 256;
    const float* bf2 = b_f2 + (size_t)i * 256;

    // q = cur + pos
    add_kernel<<<TT / 4, 256, 0, stream>>>(out, pos, q, (int)(TD / 4));
    // sampling offsets, attention logits, values
    gemm64<<<dim3(TT / 64, 4), 256, 0, stream>>>(q, Wso, bso, soff, TT, 256, 256, 0);
    gemm64<<<dim3(TT / 64, 2), 256, 0, stream>>>(q, Waw, baw, aw, TT, 128, 256, 0);
    gemm64<<<dim3(TT / 64, 4), 256, 0, stream>>>(out, Wv, bv, val, TT, 256, 256, 0);
    // deformable sampling -> att (into q, q is dead)
    sample_kernel<<<TT, 256, 0, stream>>>(val, soff, aw, q);
    // output projection -> att_o (into soff, dead)
    gemm64<<<dim3(TT / 64, 4), 256, 0, stream>>>(q, Wo, bo, soff, TT, 256, 256, 0);
    // LN1(cur + att_o) -> x (into val, dead)
    ln_kernel<<<TT, 256, 0, stream>>>(out, soff, g1 + i * 256, be1 + i * 256, val);
    // FFN in 4 row-chunks: h = relu(x@Wf1+b1); ffn_out = h@Wf2+b2 (into soff)
    for (int c = 0; c < 4; ++c) {
      const float* xA = val + (size_t)c * 5440 * 256;
      float* fo = soff + (size_t)c * 5440 * 256;
      gemm64<<<dim3(5440 / 64, 16), 256, 0, stream>>>(xA, Wf1, bf1, h, 5440, 1024, 256, 1);
      gemm64<<<dim3(5440 / 64, 4), 256, 0, stream>>>(h, Wf2, bf2, fo, 5440, 256, 1024, 0);
    }
    // LN2(x + ffn_out) -> cur
    ln_kernel<<<TT, 256, 0, stream>>>(val, soff, g2 + i * 256, be2 + i * 256, out);
  }

  tail_kernel<<<1, 16, 0, stream>>>(out + TD);
}

// Round 2
// 2178.456 us; speedup vs baseline: 2.2226x; 2.2226x over previous
//
#include <hip/hip_runtime.h>
#include <cstdint>

#define SSn 5440
#define TTn 21760
#define TD ((size_t)TTn*256)
#define NL 6

typedef short bf16x8 __attribute__((ext_vector_type(8)));
typedef float f32x4 __attribute__((ext_vector_type(4)));
typedef unsigned short u16x4 __attribute__((ext_vector_type(4)));
typedef unsigned short ushort_t;

__device__ __forceinline__ ushort_t f2b(float f) {
  uint32_t x = __float_as_uint(f);
  uint32_t r = x + 0x7FFFu + ((x >> 16) & 1u);
  return (ushort_t)(r >> 16);
}
__device__ __forceinline__ float b2f(ushort_t u) {
  return __uint_as_float((uint32_t)u << 16);
}

// ---------------------------------------------------------------------------
// Preprocess: cur (f32 + bf16), pos (bf16, + level_embed)
__global__ __launch_bounds__(256) void prep_kernel(
    const float* __restrict__ s0, const float* __restrict__ p0,
    const float* __restrict__ s1, const float* __restrict__ p1,
    const float* __restrict__ s2, const float* __restrict__ p2,
    const float* __restrict__ s3, const float* __restrict__ p3,
    const float* __restrict__ lev,
    float* __restrict__ cur, ushort_t* __restrict__ cur_b,
    ushort_t* __restrict__ pos_b)
{
  size_t idx = (size_t)blockIdx.x * 256 + threadIdx.x;
  int d = (int)(idx & 255);
  size_t bs = idx >> 8;
  int b = (int)(bs / SSn);
  int s = (int)(bs % SSn);
  int l, start, HW;
  const float* sp; const float* pp;
  if (s < 4096)      { l = 0; start = 0;    HW = 4096; sp = s0; pp = p0; }
  else if (s < 5120) { l = 1; start = 4096; HW = 1024; sp = s1; pp = p1; }
  else if (s < 5376) { l = 2; start = 5120; HW = 256;  sp = s2; pp = p2; }
  else               { l = 3; start = 5376; HW = 64;   sp = s3; pp = p3; }
  int p = s - start;
  size_t si = ((size_t)b * 256 + d) * HW + p;
  float cv = sp[si];
  cur[idx] = cv;
  cur_b[idx] = f2b(cv);
  pos_b[idx] = f2b(pp[si] + lev[l * 256 + d]);
}

// ---------------------------------------------------------------------------
// q = bf16(cur + pos)
__global__ __launch_bounds__(256) void add_kernel(
    const float* __restrict__ cur, const ushort_t* __restrict__ pos_b,
    ushort_t* __restrict__ q_b, int n4)
{
  int i = blockIdx.x * 256 + threadIdx.x;
  if (i < n4) {
    f32x4 c = ((const f32x4*)cur)[i];
    u16x4 p = ((const u16x4*)pos_b)[i];
    u16x4 o;
    #pragma unroll
    for (int j = 0; j < 4; ++j) o[j] = f2b(c[j] + b2f(p[j]));
    ((u16x4*)q_b)[i] = o;
  }
}

// ---------------------------------------------------------------------------
// Weight transpose+convert: W[K][N] f32 -> Wt[N][K] bf16. K,N multiples of 64.
__global__ __launch_bounds__(256) void wt_cvt(
    const float* __restrict__ W, ushort_t* __restrict__ Wt, int K, int N)
{
  __shared__ float tile[64][65];
  int k0 = blockIdx.x * 64, n0 = blockIdx.y * 64;
  int t = threadIdx.x;
  int r = t >> 2, c4 = (t & 3) * 16;
  #pragma unroll
  for (int i = 0; i < 4; ++i) {
    f32x4 v = *(const f32x4*)(W + (size_t)(k0 + r) * N + n0 + c4 + i * 4);
    tile[c4 + i*4 + 0][r] = v[0];
    tile[c4 + i*4 + 1][r] = v[1];
    tile[c4 + i*4 + 2][r] = v[2];
    tile[c4 + i*4 + 3][r] = v[3];
  }
  __syncthreads();
  #pragma unroll
  for (int i = 0; i < 4; ++i) {
    u16x4 o;
    #pragma unroll
    for (int j = 0; j < 4; ++j) o[j] = f2b(tile[r][c4 + i*4 + j]);
    *(u16x4*)(Wt + (size_t)(n0 + r) * K + k0 + c4 + i * 4) = o;
  }
}

// fused bias [so(256) | aw(128)] per layer
__global__ void bias_fuse(const float* __restrict__ bso,
                          const float* __restrict__ baw,
                          float* __restrict__ bsa)
{
  int l = blockIdx.x, t = threadIdx.x;
  bsa[l * 384 + t] = (t < 256) ? bso[l * 256 + t] : baw[l * 128 + t - 256];
}

// ---------------------------------------------------------------------------
// bf16 MFMA GEMM: C[M,N] = A[M,K] @ Bt[N,K]^T + bias[N]; optional relu.
// 128x128 tile, BK=64, 4 waves, global_load_lds staging, XOR-swizzled LDS.
__global__ __launch_bounds__(256) void gemm_mfma(
    const ushort_t* __restrict__ A, const ushort_t* __restrict__ Bt,
    const float* __restrict__ bias, float* __restrict__ Cf,
    ushort_t* __restrict__ Cb, int M, int N, int K, int relu)
{
  __shared__ alignas(16) ushort_t As[8192];
  __shared__ alignas(16) ushort_t Bs[8192];
  int t = threadIdx.x;
  int l = t & 63, w = t >> 6;
  int wr = w >> 1, wc = w & 1;
  int m0 = blockIdx.x * 128, n0 = blockIdx.y * 128;
  int lq = l >> 4, l15 = l & 15, r7 = l & 7;
  f32x4 acc[4][4] = {};

  for (int k0 = 0; k0 < K; k0 += 64) {
    // stage 16KB A + 16KB B: 4 issues x 256 thr x 16B each
    #pragma unroll
    for (int i = 0; i < 4; ++i) {
      int c = i * 256 + t;
      int row = c >> 3;
      int sc = (c & 7) ^ (row & 7);      // pre-swizzled global source chunk
      int ar = m0 + row; if (ar >= M) ar = M - 1;
      __builtin_amdgcn_global_load_lds(
          (const uint32_t*)(A + (size_t)ar * K + k0 + sc * 8),
          (uint32_t*)((char*)As + c * 16), 16, 0, 0);
      __builtin_amdgcn_global_load_lds(
          (const uint32_t*)(Bt + (size_t)(n0 + row) * K + k0 + sc * 8),
          (uint32_t*)((char*)Bs + c * 16), 16, 0, 0);
    }
    __syncthreads();
    #pragma unroll
    for (int ks = 0; ks < 2; ++ks) {
      bf16x8 af[4], bfr[4];
      int chs = ((ks << 2) + lq) ^ r7;   // swizzled 16B-chunk within row
      #pragma unroll
      for (int mt = 0; mt < 4; ++mt)
        af[mt] = *(const bf16x8*)((const char*)As +
                   (wr * 64 + mt * 16 + l15) * 128 + (chs << 4));
      #pragma unroll
      for (int nt = 0; nt < 4; ++nt)
        bfr[nt] = *(const bf16x8*)((const char*)Bs +
                   (wc * 64 + nt * 16 + l15) * 128 + (chs << 4));
      #pragma unroll
      for (int mt = 0; mt < 4; ++mt)
        #pragma unroll
        for (int nt = 0; nt < 4; ++nt)
          acc[mt][nt] = __builtin_amdgcn_mfma_f32_16x16x32_bf16(
              af[mt], bfr[nt], acc[mt][nt], 0, 0, 0);
    }
    __syncthreads();
  }

  int crow0 = m0 + wr * 64;
  int ccol0 = n0 + wc * 64;
  #pragma unroll
  for (int mt = 0; mt < 4; ++mt) {
    #pragma unroll
    for (int nt = 0; nt < 4; ++nt) {
      int col = ccol0 + nt * 16 + l15;
      float bv = bias[col];
      #pragma unroll
      for (int r = 0; r < 4; ++r) {
        int rowg = crow0 + mt * 16 + lq * 4 + r;
        if (rowg < M) {
          float v = acc[mt][nt][r] + bv;
          if (relu) v = fmaxf(v, 0.f);
          if (Cf) Cf[(size_t)rowg * N + col] = v;
          if (Cb) Cb[(size_t)rowg * N + col] = f2b(v);
        }
      }
    }
  }
}

// ---------------------------------------------------------------------------
// Deformable sampling: softmax + bilinear gather. One block per token.
// sa layout per token: [0..255] = offsets (pt*2+{x,y}), [256..383] = logits.
__global__ __launch_bounds__(256) void sample_kernel(
    const ushort_t* __restrict__ val, const ushort_t* __restrict__ sa,
    ushort_t* __restrict__ att)
{
  __shared__ int   sIdx[128][4];
  __shared__ float sW[128][4];
  int t = blockIdx.x;
  int b = t / SSn, s = t % SSn;
  int tid = threadIdx.x;

  if (tid < 128) {
    int pt = tid;                 // h*16 + l*4 + p
    int l = (pt >> 2) & 3;
    int st, Wt;
    if (s < 4096)      { st = 0;    Wt = 64; }
    else if (s < 5120) { st = 4096; Wt = 32; }
    else if (s < 5376) { st = 5120; Wt = 16; }
    else               { st = 5376; Wt = 8;  }
    int p = s - st;
    int iy = p / Wt, ix = p % Wt;
    float refx = (ix + 0.5f) / Wt;
    float refy = (iy + 0.5f) / Wt;

    float logit = b2f(sa[(size_t)t * 384 + 256 + pt]);
    float m = logit;
    for (int off = 1; off < 16; off <<= 1) m = fmaxf(m, __shfl_xor(m, off));
    float e = __expf(logit - m);
    float sum = e;
    for (int off = 1; off < 16; off <<= 1) sum += __shfl_xor(sum, off);
    float wa = e / sum;

    const int LW[4]  = {64, 32, 16, 8};
    const int LST[4] = {0, 4096, 5120, 5376};
    int Wl = LW[l], Hl = Wl, stl = LST[l];

    float ox = b2f(sa[(size_t)t * 384 + pt * 2]);
    float oy = b2f(sa[(size_t)t * 384 + pt * 2 + 1]);
    float x = refx * Wl + ox - 0.5f;
    float y = refy * Hl + oy - 0.5f;
    float x0f = floorf(x), y0f = floorf(y);
    int x0 = (int)x0f, y0 = (int)y0f;
    float wx1 = x - x0f, wy1 = y - y0f;
    int vbase = b * SSn + stl;
    #pragma unroll
    for (int c = 0; c < 4; ++c) {
      int dx = c & 1, dy = c >> 1;
      int xi = x0 + dx, yi = y0 + dy;
      float wgt = (dx ? wx1 : 1.f - wx1) * (dy ? wy1 : 1.f - wy1);
      bool valid = (xi >= 0) & (xi < Wl) & (yi >= 0) & (yi < Hl);
      int xc = min(max(xi, 0), Wl - 1), yc = min(max(yi, 0), Hl - 1);
      sIdx[pt][c] = vbase + yc * Wl + xc;
      sW[pt][c] = valid ? wgt * wa : 0.f;
    }
  }
  __syncthreads();

  int d = tid;
  int h = d >> 5;
  float acc = 0.f;
  #pragma unroll
  for (int k = 0; k < 16; ++k) {
    int pt = h * 16 + k;
    #pragma unroll
    for (int c = 0; c < 4; ++c)
      acc += sW[pt][c] * b2f(val[(size_t)sIdx[pt][c] * 256 + d]);
  }
  att[(size_t)t * 256 + d] = f2b(acc);
}

// ---------------------------------------------------------------------------
// LayerNorm of (a + r): r from f32 or bf16; outputs f32 + optional bf16.
__global__ __launch_bounds__(256) void ln_kernel(
    const float* __restrict__ a, const float* __restrict__ rf,
    const ushort_t* __restrict__ rb,
    const float* __restrict__ g, const float* __restrict__ be,
    float* __restrict__ of, ushort_t* __restrict__ ob)
{
  __shared__ float ps[4], ps2[4];
  int t = blockIdx.x, d = threadIdx.x;
  size_t base = (size_t)t * 256;
  float x = a[base + d] + (rf ? rf[base + d] : b2f(rb[base + d]));
  float s = x, s2 = x * x;
  #pragma unroll
  for (int off = 1; off < 64; off <<= 1) {
    s  += __shfl_xor(s, off);
    s2 += __shfl_xor(s2, off);
  }
  int w = d >> 6, lane = d & 63;
  if (lane == 0) { ps[w] = s; ps2[w] = s2; }
  __syncthreads();
  if (d == 0) {
    ps[0]  = ps[0] + ps[1] + ps[2] + ps[3];
    ps2[0] = ps2[0] + ps2[1] + ps2[2] + ps2[3];
  }
  __syncthreads();
  float mean = ps[0] * (1.f / 256.f);
  float var = ps2[0] * (1.f / 256.f) - mean * mean;
  float y = (x - mean) * rsqrtf(var + 1e-5f) * g[d] + be[d];
  of[base + d] = y;
  if (ob) ob[base + d] = f2b(y);
}

// ---------------------------------------------------------------------------
__global__ void tail_kernel(float* __restrict__ o) {
  const float v[12] = {64.f, 64.f, 32.f, 32.f, 16.f, 16.f, 8.f, 8.f,
                       0.f, 4096.f, 5120.f, 5376.f};
  int i = threadIdx.x;
  if (i < 12) o[i] = v[i];
}

// ---------------------------------------------------------------------------
extern "C" void kernel_launch(void* const* d_in, const int* in_sizes, int n_in,
                              void* d_out, int out_size, void* d_ws, size_t ws_size,
                              hipStream_t stream)
{
  const float* s0  = (const float*)d_in[0];
  const float* p0  = (const float*)d_in[1];
  const float* s1  = (const float*)d_in[2];
  const float* p1  = (const float*)d_in[3];
  const float* s2  = (const float*)d_in[4];
  const float* p2  = (const float*)d_in[5];
  const float* s3  = (const float*)d_in[6];
  const float* p3  = (const float*)d_in[7];
  const float* lev = (const float*)d_in[8];
  const float* W_so = (const float*)d_in[9];
  const float* b_so = (const float*)d_in[10];
  const float* W_aw = (const float*)d_in[11];
  const float* b_aw = (const float*)d_in[12];
  const float* W_v  = (const float*)d_in[13];
  const float* b_v  = (const float*)d_in[14];
  const float* W_o  = (const float*)d_in[15];
  const float* b_o  = (const float*)d_in[16];
  const float* g1   = (const float*)d_in[17];
  const float* be1  = (const float*)d_in[18];
  const float* W_f1 = (const float*)d_in[19];
  const float* b_f1 = (const float*)d_in[20];
  const float* W_f2 = (const float*)d_in[21];
  const float* b_f2 = (const float*)d_in[22];
  const float* g2   = (const float*)d_in[23];
  const float* be2  = (const float*)d_in[24];

  float* out = (float*)d_out;
  float* ws  = (float*)d_ws;

  // workspace layout (float units)
  ushort_t* pos_b = (ushort_t*)ws;                          // 0.5 TD
  float*    x_f   = ws + TD / 2;                            // 1 TD (also att_o)
  ushort_t* q_b   = (ushort_t*)(ws + TD / 2 + TD);          // 0.5 TD (also att)
  ushort_t* cur_b = (ushort_t*)(ws + 2 * TD);               // 0.5 TD
  ushort_t* sa_b  = (ushort_t*)(ws + 2 * TD + TD / 2);      // 0.75 TD
  ushort_t* x_b   = sa_b;                                   // reuse (sa dead)
  ushort_t* val_b = (ushort_t*)(ws + 3 * TD + TD / 4);      // 0.5 TD
  ushort_t* ffn_b = val_b;                                  // reuse (val dead)
  ushort_t* h_b   = (ushort_t*)(ws + 3 * TD + 3 * (TD / 4));// 1 TD (10880x1024)
  ushort_t* wt    = (ushort_t*)(ws + 4 * TD + 3 * (TD / 4));// 4,521,984 bf16
  float*    bsa   = ws + 4 * TD + 3 * (TD / 4) + 2260992;   // 6*384 f32
  float*    atto  = x_f;

  const size_t LW = 753664;  // per-layer transposed-weight stride (bf16 elems)

  // one-time weight prep
  for (int i = 0; i < NL; ++i) {
    ushort_t* wl = wt + (size_t)i * LW;
    wt_cvt<<<dim3(4, 4),  256, 0, stream>>>(W_so + (size_t)i * 65536,  wl + 0,      256, 256);
    wt_cvt<<<dim3(4, 2),  256, 0, stream>>>(W_aw + (size_t)i * 32768,  wl + 65536,  256, 128);
    wt_cvt<<<dim3(4, 4),  256, 0, stream>>>(W_v  + (size_t)i * 65536,  wl + 98304,  256, 256);
    wt_cvt<<<dim3(4, 4),  256, 0, stream>>>(W_o  + (size_t)i * 65536,  wl + 163840, 256, 256);
    wt_cvt<<<dim3(4, 16), 256, 0, stream>>>(W_f1 + (size_t)i * 262144, wl + 229376, 256, 1024);
    wt_cvt<<<dim3(16, 4), 256, 0, stream>>>(W_f2 + (size_t)i * 262144, wl + 491520, 1024, 256);
  }
  bias_fuse<<<NL, 384, 0, stream>>>(b_so, b_aw, bsa);

  prep_kernel<<<TTn, 256, 0, stream>>>(s0, p0, s1, p1, s2, p2, s3, p3, lev,
                                       out, cur_b, pos_b);

  for (int i = 0; i < NL; ++i) {
    ushort_t* wl = wt + (size_t)i * LW;
    const float* bv  = b_v  + (size_t)i * 256;
    const float* bo  = b_o  + (size_t)i * 256;
    const float* bf1 = b_f1 + (size_t)i * 1024;
    const float* bf2 = b_f2 + (size_t)i * 256;

    add_kernel<<<5440, 256, 0, stream>>>(out, pos_b, q_b, (int)(TD / 4));
    // fused soff+aw projection: N=384
    gemm_mfma<<<dim3(170, 3), 256, 0, stream>>>(q_b, wl + 0, bsa + i * 384,
                                                nullptr, sa_b, TTn, 384, 256, 0);
    // values
    gemm_mfma<<<dim3(170, 2), 256, 0, stream>>>(cur_b, wl + 98304, bv,
                                                nullptr, val_b, TTn, 256, 256, 0);
    // deformable sampling -> att (bf16, into q_b)
    sample_kernel<<<TTn, 256, 0, stream>>>(val_b, sa_b, q_b);
    // output projection -> att_o (f32, into x_f region)
    gemm_mfma<<<dim3(170, 2), 256, 0, stream>>>(q_b, wl + 163840, bo,
                                                atto, nullptr, TTn, 256, 256, 0);
    // LN1(cur + att_o) -> x_f (in-place over atto) + x_b
    ln_kernel<<<TTn, 256, 0, stream>>>(out, atto, nullptr,
                                       g1 + i * 256, be1 + i * 256, x_f, x_b);
    // FFN, 2 row-chunks of 10880
    for (int c = 0; c < 2; ++c) {
      const ushort_t* xa = x_b + (size_t)c * 10880 * 256;
      ushort_t* fo = ffn_b + (size_t)c * 10880 * 256;
      gemm_mfma<<<dim3(85, 8), 256, 0, stream>>>(xa, wl + 229376, bf1,
                                                 nullptr, h_b, 10880, 1024, 256, 1);
      gemm_mfma<<<dim3(85, 2), 256, 0, stream>>>(h_b, wl + 491520, bf2,
                                                 nullptr, fo, 10880, 256, 1024, 0);
    }
    // LN2(x + ffn) -> cur (f32 + bf16)
    ln_kernel<<<TTn, 256, 0, stream>>>(x_f, nullptr, ffn_b,
                                       g2 + i * 256, be2 + i * 256, out, cur_b);
  }

  tail_kernel<<<1, 16, 0, stream>>>(out + TD);
}

// Round 3
// 1153.680 us; speedup vs baseline: 4.1968x; 1.8883x over previous
//
#include <hip/hip_runtime.h>
#include <cstdint>

#define SSn 5440
#define TTn 21760
#define TD ((size_t)TTn*256)
#define NL 6

typedef short bf16x8 __attribute__((ext_vector_type(8)));
typedef float f32x4 __attribute__((ext_vector_type(4)));
typedef unsigned short u16x4 __attribute__((ext_vector_type(4)));
typedef unsigned short ushort_t;

__device__ __forceinline__ ushort_t f2b(float f) {
  uint32_t x = __float_as_uint(f);
  uint32_t r = x + 0x7FFFu + ((x >> 16) & 1u);
  return (ushort_t)(r >> 16);
}
__device__ __forceinline__ float b2f(ushort_t u) {
  return __uint_as_float((uint32_t)u << 16);
}

// ---------------------------------------------------------------------------
// Preprocess: cur (f32 + bf16), pos (bf16), q0 = bf16(cur+pos)
__global__ __launch_bounds__(256) void prep_kernel(
    const float* __restrict__ s0, const float* __restrict__ p0,
    const float* __restrict__ s1, const float* __restrict__ p1,
    const float* __restrict__ s2, const float* __restrict__ p2,
    const float* __restrict__ s3, const float* __restrict__ p3,
    const float* __restrict__ lev,
    float* __restrict__ cur, ushort_t* __restrict__ cur_b,
    ushort_t* __restrict__ pos_b, ushort_t* __restrict__ q_b)
{
  size_t idx = (size_t)blockIdx.x * 256 + threadIdx.x;
  int d = (int)(idx & 255);
  size_t bs = idx >> 8;
  int b = (int)(bs / SSn);
  int s = (int)(bs % SSn);
  int l, start, HW;
  const float* sp; const float* pp;
  if (s < 4096)      { l = 0; start = 0;    HW = 4096; sp = s0; pp = p0; }
  else if (s < 5120) { l = 1; start = 4096; HW = 1024; sp = s1; pp = p1; }
  else if (s < 5376) { l = 2; start = 5120; HW = 256;  sp = s2; pp = p2; }
  else               { l = 3; start = 5376; HW = 64;   sp = s3; pp = p3; }
  int p = s - start;
  size_t si = ((size_t)b * 256 + d) * HW + p;
  float cv = sp[si];
  float pv = pp[si] + lev[l * 256 + d];
  cur[idx] = cv;
  cur_b[idx] = f2b(cv);
  pos_b[idx] = f2b(pv);
  q_b[idx] = f2b(cv + pv);
}

// ---------------------------------------------------------------------------
// Batched weight transpose+convert: all 6 layers x 6 weights in one launch.
// W[K][N] f32 -> Wt[N][K] bf16, 64x64 tiles. 184 tiles/layer, 1104 blocks.
__global__ __launch_bounds__(256) void wprep_kernel(
    const float* __restrict__ W_so, const float* __restrict__ W_aw,
    const float* __restrict__ W_v,  const float* __restrict__ W_o,
    const float* __restrict__ W_f1, const float* __restrict__ W_f2,
    ushort_t* __restrict__ wt)
{
  __shared__ float tile[64][65];
  int bx = blockIdx.x;
  int layer = bx / 184, r = bx % 184;
  int type, ti;
  if (r < 16)       { type = 0; ti = r; }
  else if (r < 24)  { type = 1; ti = r - 16; }
  else if (r < 40)  { type = 2; ti = r - 24; }
  else if (r < 56)  { type = 3; ti = r - 40; }
  else if (r < 120) { type = 4; ti = r - 56; }
  else              { type = 5; ti = r - 120; }
  const float* src;
  int K, N, dof;
  switch (type) {
    case 0: src = W_so + (size_t)layer * 65536;  K = 256;  N = 256;  dof = 0;      break;
    case 1: src = W_aw + (size_t)layer * 32768;  K = 256;  N = 128;  dof = 65536;  break;
    case 2: src = W_v  + (size_t)layer * 65536;  K = 256;  N = 256;  dof = 98304;  break;
    case 3: src = W_o  + (size_t)layer * 65536;  K = 256;  N = 256;  dof = 163840; break;
    case 4: src = W_f1 + (size_t)layer * 262144; K = 256;  N = 1024; dof = 229376; break;
    default:src = W_f2 + (size_t)layer * 262144; K = 1024; N = 256;  dof = 491520; break;
  }
  int Kt = K >> 6;
  int k0 = (ti % Kt) * 64, n0 = (ti / Kt) * 64;
  ushort_t* dst = wt + (size_t)layer * 753664 + dof;
  int t = threadIdx.x;
  int rr = t >> 2, c4 = (t & 3) * 16;
  #pragma unroll
  for (int i = 0; i < 4; ++i) {
    f32x4 v = *(const f32x4*)(src + (size_t)(k0 + rr) * N + n0 + c4 + i * 4);
    tile[c4 + i*4 + 0][rr] = v[0];
    tile[c4 + i*4 + 1][rr] = v[1];
    tile[c4 + i*4 + 2][rr] = v[2];
    tile[c4 + i*4 + 3][rr] = v[3];
  }
  __syncthreads();
  #pragma unroll
  for (int i = 0; i < 4; ++i) {
    u16x4 o;
    #pragma unroll
    for (int j = 0; j < 4; ++j) o[j] = f2b(tile[rr][c4 + i*4 + j]);
    *(u16x4*)(dst + (size_t)(n0 + rr) * K + k0 + c4 + i * 4) = o;
  }
}

// fused bias [so(256) | aw(128)] per layer
__global__ void bias_fuse(const float* __restrict__ bso,
                          const float* __restrict__ baw,
                          float* __restrict__ bsa)
{
  int l = blockIdx.x, t = threadIdx.x;
  bsa[l * 384 + t] = (t < 256) ? bso[l * 256 + t] : baw[l * 128 + t - 256];
}

// ---------------------------------------------------------------------------
// bf16 MFMA GEMM: C[M,N] = A[M,K] @ Bt[N,K]^T + bias[N]; optional relu.
// 128x128 tile, BK=64, 4 waves, global_load_lds staging, XOR-swizzled LDS.
__global__ __launch_bounds__(256) void gemm_mfma(
    const ushort_t* __restrict__ A, const ushort_t* __restrict__ Bt,
    const float* __restrict__ bias, float* __restrict__ Cf,
    ushort_t* __restrict__ Cb, int M, int N, int K, int relu)
{
  __shared__ alignas(16) ushort_t As[8192];
  __shared__ alignas(16) ushort_t Bs[8192];
  int t = threadIdx.x;
  int l = t & 63, w = t >> 6;
  int wr = w >> 1, wc = w & 1;
  int m0 = blockIdx.x * 128, n0 = blockIdx.y * 128;
  int lq = l >> 4, l15 = l & 15, r7 = l & 7;
  f32x4 acc[4][4] = {};

  for (int k0 = 0; k0 < K; k0 += 64) {
    #pragma unroll
    for (int i = 0; i < 4; ++i) {
      int c = i * 256 + t;
      int row = c >> 3;
      int sc = (c & 7) ^ (row & 7);
      __builtin_amdgcn_global_load_lds(
          (const uint32_t*)(A + (size_t)(m0 + row) * K + k0 + sc * 8),
          (uint32_t*)((char*)As + c * 16), 16, 0, 0);
      __builtin_amdgcn_global_load_lds(
          (const uint32_t*)(Bt + (size_t)(n0 + row) * K + k0 + sc * 8),
          (uint32_t*)((char*)Bs + c * 16), 16, 0, 0);
    }
    __syncthreads();
    #pragma unroll
    for (int ks = 0; ks < 2; ++ks) {
      bf16x8 af[4], bfr[4];
      int chs = ((ks << 2) + lq) ^ r7;
      #pragma unroll
      for (int mt = 0; mt < 4; ++mt)
        af[mt] = *(const bf16x8*)((const char*)As +
                   (wr * 64 + mt * 16 + l15) * 128 + (chs << 4));
      #pragma unroll
      for (int nt = 0; nt < 4; ++nt)
        bfr[nt] = *(const bf16x8*)((const char*)Bs +
                   (wc * 64 + nt * 16 + l15) * 128 + (chs << 4));
      #pragma unroll
      for (int mt = 0; mt < 4; ++mt)
        #pragma unroll
        for (int nt = 0; nt < 4; ++nt)
          acc[mt][nt] = __builtin_amdgcn_mfma_f32_16x16x32_bf16(
              af[mt], bfr[nt], acc[mt][nt], 0, 0, 0);
    }
    __syncthreads();
  }

  int crow0 = m0 + wr * 64;
  int ccol0 = n0 + wc * 64;
  #pragma unroll
  for (int mt = 0; mt < 4; ++mt) {
    #pragma unroll
    for (int nt = 0; nt < 4; ++nt) {
      int col = ccol0 + nt * 16 + l15;
      float bv = bias[col];
      #pragma unroll
      for (int r = 0; r < 4; ++r) {
        int rowg = crow0 + mt * 16 + lq * 4 + r;
        float v = acc[mt][nt][r] + bv;
        if (relu) v = fmaxf(v, 0.f);
        if (Cf) Cf[(size_t)rowg * N + col] = v;
        if (Cb) Cb[(size_t)rowg * N + col] = f2b(v);
      }
    }
  }
}

// ---------------------------------------------------------------------------
// Fused GEMM (N=256) + residual + LayerNorm. Tile 128x256, 8 waves.
// Of = LN(A@Bt^T + bias + res); Ob = bf16(Of); Oq = bf16(Of + pos) optional.
__global__ __launch_bounds__(512) void gemm_ln(
    const ushort_t* __restrict__ A, const ushort_t* __restrict__ Bt,
    const float* __restrict__ bias, const float* __restrict__ res,
    const float* __restrict__ g, const float* __restrict__ be,
    float* __restrict__ Of, ushort_t* __restrict__ Ob,
    ushort_t* __restrict__ Oq, const ushort_t* __restrict__ posb,
    int M, int K)
{
  __shared__ alignas(16) ushort_t As[128 * 64];   // 16 KB
  __shared__ alignas(16) ushort_t Bs[256 * 64];   // 32 KB
  __shared__ float psum[128][4];
  __shared__ float psum2[128][4];
  __shared__ float2 mstd[128];
  int t = threadIdx.x;
  int l = t & 63, w = t >> 6;
  int wr = w >> 2, wc = w & 3;
  int m0 = blockIdx.x * 128;
  int lq = l >> 4, l15 = l & 15, r7 = l & 7;
  f32x4 acc[4][4] = {};

  for (int k0 = 0; k0 < K; k0 += 64) {
    #pragma unroll
    for (int i = 0; i < 2; ++i) {          // A: 1024 chunks
      int c = i * 512 + t;
      int row = c >> 3;
      int sc = (c & 7) ^ (row & 7);
      __builtin_amdgcn_global_load_lds(
          (const uint32_t*)(A + (size_t)(m0 + row) * K + k0 + sc * 8),
          (uint32_t*)((char*)As + c * 16), 16, 0, 0);
    }
    #pragma unroll
    for (int i = 0; i < 4; ++i) {          // B: 2048 chunks
      int c = i * 512 + t;
      int row = c >> 3;
      int sc = (c & 7) ^ (row & 7);
      __builtin_amdgcn_global_load_lds(
          (const uint32_t*)(Bt + (size_t)row * K + k0 + sc * 8),
          (uint32_t*)((char*)Bs + c * 16), 16, 0, 0);
    }
    __syncthreads();
    #pragma unroll
    for (int ks = 0; ks < 2; ++ks) {
      bf16x8 af[4], bfr[4];
      int chs = ((ks << 2) + lq) ^ r7;
      #pragma unroll
      for (int mt = 0; mt < 4; ++mt)
        af[mt] = *(const bf16x8*)((const char*)As +
                   (wr * 64 + mt * 16 + l15) * 128 + (chs << 4));
      #pragma unroll
      for (int nt = 0; nt < 4; ++nt)
        bfr[nt] = *(const bf16x8*)((const char*)Bs +
                   (wc * 64 + nt * 16 + l15) * 128 + (chs << 4));
      #pragma unroll
      for (int mt = 0; mt < 4; ++mt)
        #pragma unroll
        for (int nt = 0; nt < 4; ++nt)
          acc[mt][nt] = __builtin_amdgcn_mfma_f32_16x16x32_bf16(
              af[mt], bfr[nt], acc[mt][nt], 0, 0, 0);
    }
    __syncthreads();
  }

  // ---- epilogue: bias + residual, then LN over the 256-wide row ----
  float gv[4], bev[4], biasv[4];
  #pragma unroll
  for (int nt = 0; nt < 4; ++nt) {
    int col = wc * 64 + nt * 16 + l15;
    gv[nt] = g[col]; bev[nt] = be[col]; biasv[nt] = bias[col];
  }
  #pragma unroll
  for (int mt = 0; mt < 4; ++mt) {
    #pragma unroll
    for (int r = 0; r < 4; ++r) {
      int rowg = m0 + wr * 64 + mt * 16 + lq * 4 + r;
      #pragma unroll
      for (int nt = 0; nt < 4; ++nt) {
        int col = wc * 64 + nt * 16 + l15;
        acc[mt][nt][r] += biasv[nt] + res[(size_t)rowg * 256 + col];
      }
    }
  }
  // per-row partial sums (64 cols per wave)
  #pragma unroll
  for (int mt = 0; mt < 4; ++mt) {
    #pragma unroll
    for (int r = 0; r < 4; ++r) {
      float s = 0.f, s2 = 0.f;
      #pragma unroll
      for (int nt = 0; nt < 4; ++nt) {
        float v = acc[mt][nt][r];
        s += v; s2 += v * v;
      }
      #pragma unroll
      for (int off = 1; off < 16; off <<= 1) {
        s  += __shfl_xor(s, off);
        s2 += __shfl_xor(s2, off);
      }
      if (l15 == 0) {
        int rloc = wr * 64 + mt * 16 + lq * 4 + r;
        psum[rloc][wc] = s;
        psum2[rloc][wc] = s2;
      }
    }
  }
  __syncthreads();
  if (t < 128) {
    f32x4 a = *(const f32x4*)psum[t];
    f32x4 b = *(const f32x4*)psum2[t];
    float s = a[0] + a[1] + a[2] + a[3];
    float s2 = b[0] + b[1] + b[2] + b[3];
    float mean = s * (1.f / 256.f);
    float var = s2 * (1.f / 256.f) - mean * mean;
    mstd[t] = make_float2(mean, rsqrtf(var + 1e-5f));
  }
  __syncthreads();
  #pragma unroll
  for (int mt = 0; mt < 4; ++mt) {
    #pragma unroll
    for (int r = 0; r < 4; ++r) {
      int rloc = wr * 64 + mt * 16 + lq * 4 + r;
      int rowg = m0 + rloc;
      float2 ms = mstd[rloc];
      #pragma unroll
      for (int nt = 0; nt < 4; ++nt) {
        int col = wc * 64 + nt * 16 + l15;
        float y = (acc[mt][nt][r] - ms.x) * ms.y * gv[nt] + bev[nt];
        size_t o = (size_t)rowg * 256 + col;
        Of[o] = y;
        Ob[o] = f2b(y);
        if (Oq) Oq[o] = f2b(y + b2f(posb[o]));
      }
    }
  }
}

// ---------------------------------------------------------------------------
// Deformable sampling: 2 tokens/block, 256 threads. Each thread owns a
// channel PAIR (u32 loads). Idx/weights packed as int4/float4 per point.
__global__ __launch_bounds__(256) void sample_kernel(
    const ushort_t* __restrict__ val, const ushort_t* __restrict__ sa,
    ushort_t* __restrict__ att)
{
  __shared__ int4   sIdx4[2][128];
  __shared__ float4 sW4[2][128];
  int tid = threadIdx.x;
  int half = tid >> 7, u = tid & 127;
  int t = blockIdx.x * 2 + half;
  int b = t / SSn, s = t % SSn;

  { // setup: pt = u for this half's token
    int pt = u;
    int lvl = (pt >> 2) & 3;
    int st, Wt;
    if (s < 4096)      { st = 0;    Wt = 64; }
    else if (s < 5120) { st = 4096; Wt = 32; }
    else if (s < 5376) { st = 5120; Wt = 16; }
    else               { st = 5376; Wt = 8;  }
    int p = s - st;
    int iy = p / Wt, ix = p % Wt;
    float refx = (ix + 0.5f) / Wt;
    float refy = (iy + 0.5f) / Wt;

    float logit = b2f(sa[(size_t)t * 384 + 256 + pt]);
    float m = logit;
    #pragma unroll
    for (int off = 1; off < 16; off <<= 1) m = fmaxf(m, __shfl_xor(m, off));
    float e = __expf(logit - m);
    float sum = e;
    #pragma unroll
    for (int off = 1; off < 16; off <<= 1) sum += __shfl_xor(sum, off);
    float wa = e / sum;

    const int LWt[4]  = {64, 32, 16, 8};
    const int LST[4] = {0, 4096, 5120, 5376};
    int Wl = LWt[lvl], Hl = Wl, stl = LST[lvl];

    float ox = b2f(sa[(size_t)t * 384 + pt * 2]);
    float oy = b2f(sa[(size_t)t * 384 + pt * 2 + 1]);
    float x = refx * Wl + ox - 0.5f;
    float y = refy * Hl + oy - 0.5f;
    float x0f = floorf(x), y0f = floorf(y);
    int x0 = (int)x0f, y0 = (int)y0f;
    float wx1 = x - x0f, wy1 = y - y0f;
    int vbase = b * SSn + stl;
    int4 idx4; float4 w4;
    int* ip = (int*)&idx4; float* wp = (float*)&w4;
    #pragma unroll
    for (int c = 0; c < 4; ++c) {
      int dx = c & 1, dy = c >> 1;
      int xi = x0 + dx, yi = y0 + dy;
      float wgt = (dx ? wx1 : 1.f - wx1) * (dy ? wy1 : 1.f - wy1);
      bool valid = (xi >= 0) & (xi < Wl) & (yi >= 0) & (yi < Hl);
      int xc = min(max(xi, 0), Wl - 1), yc = min(max(yi, 0), Hl - 1);
      ip[c] = vbase + yc * Wl + xc;
      wp[c] = valid ? wgt * wa : 0.f;
    }
    sIdx4[half][pt] = idx4;
    sW4[half][pt] = w4;
  }
  __syncthreads();

  int h = u >> 4, j = u & 15;
  int c0 = h * 32 + j * 2;
  float acc0 = 0.f, acc1 = 0.f;
  #pragma unroll
  for (int k = 0; k < 16; ++k) {
    int pt = h * 16 + k;
    int4 idx4 = sIdx4[half][pt];
    float4 w4 = sW4[half][pt];
    const int* ip = (const int*)&idx4;
    const float* wp = (const float*)&w4;
    #pragma unroll
    for (int c = 0; c < 4; ++c) {
      uint32_t uv = *(const uint32_t*)(val + ((size_t)ip[c] << 8) + c0);
      float v0 = __uint_as_float(uv << 16);
      float v1 = __uint_as_float(uv & 0xFFFF0000u);
      acc0 += wp[c] * v0;
      acc1 += wp[c] * v1;
    }
  }
  uint32_t pk = (uint32_t)f2b(acc0) | ((uint32_t)f2b(acc1) << 16);
  *(uint32_t*)(att + (size_t)t * 256 + c0) = pk;
}

// ---------------------------------------------------------------------------
__global__ void tail_kernel(float* __restrict__ o) {
  const float v[12] = {64.f, 64.f, 32.f, 32.f, 16.f, 16.f, 8.f, 8.f,
                       0.f, 4096.f, 5120.f, 5376.f};
  int i = threadIdx.x;
  if (i < 12) o[i] = v[i];
}

// ---------------------------------------------------------------------------
extern "C" void kernel_launch(void* const* d_in, const int* in_sizes, int n_in,
                              void* d_out, int out_size, void* d_ws, size_t ws_size,
                              hipStream_t stream)
{
  const float* s0  = (const float*)d_in[0];
  const float* p0  = (const float*)d_in[1];
  const float* s1  = (const float*)d_in[2];
  const float* p1  = (const float*)d_in[3];
  const float* s2  = (const float*)d_in[4];
  const float* p2  = (const float*)d_in[5];
  const float* s3  = (const float*)d_in[6];
  const float* p3  = (const float*)d_in[7];
  const float* lev = (const float*)d_in[8];
  const float* W_so = (const float*)d_in[9];
  const float* b_so = (const float*)d_in[10];
  const float* W_aw = (const float*)d_in[11];
  const float* b_aw = (const float*)d_in[12];
  const float* W_v  = (const float*)d_in[13];
  const float* b_v  = (const float*)d_in[14];
  const float* W_o  = (const float*)d_in[15];
  const float* b_o  = (const float*)d_in[16];
  const float* g1   = (const float*)d_in[17];
  const float* be1  = (const float*)d_in[18];
  const float* W_f1 = (const float*)d_in[19];
  const float* b_f1 = (const float*)d_in[20];
  const float* W_f2 = (const float*)d_in[21];
  const float* b_f2 = (const float*)d_in[22];
  const float* g2   = (const float*)d_in[23];
  const float* be2  = (const float*)d_in[24];

  float* out = (float*)d_out;
  float* ws  = (float*)d_ws;

  // workspace layout (f32 units). Total ~5.41 TD = 120.5 MB.
  ushort_t* pos_b = (ushort_t*)ws;                          // 0.5 TD
  float*    x_f   = ws + TD / 2;                            // 1 TD
  ushort_t* q_b   = (ushort_t*)(ws + TD / 2 + TD);          // 0.5 TD (q / att)
  ushort_t* cur_b = (ushort_t*)(ws + 2 * TD);               // 0.5 TD
  ushort_t* x_b   = (ushort_t*)(ws + 2 * TD + TD / 2);      // 0.5 TD
  // H region: 2 TD. Phase1: sa_b (0.75 TD) + val_b (0.5 TD). Phase3: h_b (2 TD).
  ushort_t* sa_b  = (ushort_t*)(ws + 3 * TD);
  ushort_t* val_b = (ushort_t*)(ws + 3 * TD + 3 * (TD / 4));
  ushort_t* h_b   = (ushort_t*)(ws + 3 * TD);
  ushort_t* wt    = (ushort_t*)(ws + 5 * TD);               // 4,521,984 bf16
  float*    bsa   = ws + 5 * TD + 2260992;                  // 6*384 f32

  const size_t LW = 753664;  // per-layer transposed-weight stride (bf16)

  wprep_kernel<<<1104, 256, 0, stream>>>(W_so, W_aw, W_v, W_o, W_f1, W_f2, wt);
  bias_fuse<<<NL, 384, 0, stream>>>(b_so, b_aw, bsa);
  prep_kernel<<<TTn, 256, 0, stream>>>(s0, p0, s1, p1, s2, p2, s3, p3, lev,
                                       out, cur_b, pos_b, q_b);

  for (int i = 0; i < NL; ++i) {
    ushort_t* wl = wt + (size_t)i * LW;
    const float* bv  = b_v  + (size_t)i * 256;
    const float* bo  = b_o  + (size_t)i * 256;
    const float* bf1 = b_f1 + (size_t)i * 1024;
    const float* bf2 = b_f2 + (size_t)i * 256;

    // fused soff+aw projection: N=384 (reads q_b)
    gemm_mfma<<<dim3(170, 3), 256, 0, stream>>>(q_b, wl + 0, bsa + i * 384,
                                                nullptr, sa_b, TTn, 384, 256, 0);
    // values (reads cur_b)
    gemm_mfma<<<dim3(170, 2), 256, 0, stream>>>(cur_b, wl + 98304, bv,
                                                nullptr, val_b, TTn, 256, 256, 0);
    // deformable sampling -> att (bf16, overwrites q_b)
    sample_kernel<<<TTn / 2, 256, 0, stream>>>(val_b, sa_b, q_b);
    // Wo projection + residual(cur f32) + LN1 -> x_f, x_b
    gemm_ln<<<170, 512, 0, stream>>>(q_b, wl + 163840, bo, out,
                                     g1 + i * 256, be1 + i * 256,
                                     x_f, x_b, nullptr, nullptr, TTn, 256);
    // FFN1 (relu) -> h_b  (full M)
    gemm_mfma<<<dim3(170, 8), 256, 0, stream>>>(x_b, wl + 229376, bf1,
                                                nullptr, h_b, TTn, 1024, 256, 1);
    // FFN2 + residual(x_f) + LN2 -> out (f32), cur_b, q_b(next = y+pos)
    gemm_ln<<<170, 512, 0, stream>>>(h_b, wl + 491520, bf2, x_f,
                                     g2 + i * 256, be2 + i * 256,
                                     out, cur_b, q_b, pos_b, TTn, 1024);
  }

  tail_kernel<<<1, 16, 0, stream>>>(out + TD);
}

// Round 4
// 952.508 us; speedup vs baseline: 5.0832x; 1.2112x over previous
//
#include <hip/hip_runtime.h>
#include <cstdint>

#define SSn 5440
#define TTn 21760
#define TD ((size_t)TTn*256)
#define NL 6

typedef short bf16x8 __attribute__((ext_vector_type(8)));
typedef float f32x4 __attribute__((ext_vector_type(4)));
typedef unsigned short u16x4 __attribute__((ext_vector_type(4)));
typedef unsigned short ushort_t;

__device__ __forceinline__ ushort_t f2b(float f) {
  uint32_t x = __float_as_uint(f);
  uint32_t r = x + 0x7FFFu + ((x >> 16) & 1u);
  return (ushort_t)(r >> 16);
}
__device__ __forceinline__ float b2f(ushort_t u) {
  return __uint_as_float((uint32_t)u << 16);
}

// ---------------------------------------------------------------------------
// Preprocess v2: tiled 64x64 LDS transpose. 340 tiles/batch x 4 = 1360 blocks.
// Outputs: cur (f32), cur_b, pos_b, q_b (bf16).
__global__ __launch_bounds__(256) void prep_kernel(
    const float* __restrict__ s0, const float* __restrict__ p0,
    const float* __restrict__ s1, const float* __restrict__ p1,
    const float* __restrict__ s2, const float* __restrict__ p2,
    const float* __restrict__ s3, const float* __restrict__ p3,
    const float* __restrict__ lev,
    float* __restrict__ cur, ushort_t* __restrict__ cur_b,
    ushort_t* __restrict__ pos_b, ushort_t* __restrict__ q_b)
{
  __shared__ float ts[64][65];
  __shared__ float tp[64][65];
  int bx = blockIdx.x;
  int b = bx / 340, r = bx % 340;
  const float *sp, *pp; int l, HW, start, dt, ptile;
  if (r < 256)      { l=0; HW=4096; start=0;    sp=s0; pp=p0; dt=r>>6;       ptile=r&63; }
  else if (r < 320) { l=1; HW=1024; start=4096; sp=s1; pp=p1; dt=(r-256)>>4; ptile=(r-256)&15; }
  else if (r < 336) { l=2; HW=256;  start=5120; sp=s2; pp=p2; dt=(r-320)>>2; ptile=(r-320)&3; }
  else              { l=3; HW=64;   start=5376; sp=s3; pp=p3; dt=r-336;      ptile=0; }
  int d0 = dt * 64, pp0 = ptile * 64;
  int t = threadIdx.x;
  int rr = t >> 2, c4 = (t & 3) * 16;
  size_t ibase = ((size_t)b * 256 + d0 + rr) * HW + pp0;
  #pragma unroll
  for (int i = 0; i < 4; ++i) {
    f32x4 v = *(const f32x4*)(sp + ibase + c4 + i * 4);
    f32x4 w = *(const f32x4*)(pp + ibase + c4 + i * 4);
    #pragma unroll
    for (int j = 0; j < 4; ++j) { ts[c4 + i*4 + j][rr] = v[j]; tp[c4 + i*4 + j][rr] = w[j]; }
  }
  __syncthreads();
  int token = start + pp0 + rr;
  size_t obase = ((size_t)b * SSn + token) * 256 + d0;
  #pragma unroll
  for (int i = 0; i < 4; ++i) {
    f32x4 cv; u16x4 cb, pb, qb;
    #pragma unroll
    for (int j = 0; j < 4; ++j) {
      float c = ts[rr][c4 + i*4 + j];
      float p = tp[rr][c4 + i*4 + j] + lev[l * 256 + d0 + c4 + i*4 + j];
      cv[j] = c; cb[j] = f2b(c); pb[j] = f2b(p); qb[j] = f2b(c + p);
    }
    *(f32x4*)(cur + obase + c4 + i*4) = cv;
    *(u16x4*)(cur_b + obase + c4 + i*4) = cb;
    *(u16x4*)(pos_b + obase + c4 + i*4) = pb;
    *(u16x4*)(q_b + obase + c4 + i*4) = qb;
  }
}

// ---------------------------------------------------------------------------
// Batched weight transpose+convert (unchanged)
__global__ __launch_bounds__(256) void wprep_kernel(
    const float* __restrict__ W_so, const float* __restrict__ W_aw,
    const float* __restrict__ W_v,  const float* __restrict__ W_o,
    const float* __restrict__ W_f1, const float* __restrict__ W_f2,
    ushort_t* __restrict__ wt)
{
  __shared__ float tile[64][65];
  int bx = blockIdx.x;
  int layer = bx / 184, r = bx % 184;
  int type, ti;
  if (r < 16)       { type = 0; ti = r; }
  else if (r < 24)  { type = 1; ti = r - 16; }
  else if (r < 40)  { type = 2; ti = r - 24; }
  else if (r < 56)  { type = 3; ti = r - 40; }
  else if (r < 120) { type = 4; ti = r - 56; }
  else              { type = 5; ti = r - 120; }
  const float* src;
  int K, N, dof;
  switch (type) {
    case 0: src = W_so + (size_t)layer * 65536;  K = 256;  N = 256;  dof = 0;      break;
    case 1: src = W_aw + (size_t)layer * 32768;  K = 256;  N = 128;  dof = 65536;  break;
    case 2: src = W_v  + (size_t)layer * 65536;  K = 256;  N = 256;  dof = 98304;  break;
    case 3: src = W_o  + (size_t)layer * 65536;  K = 256;  N = 256;  dof = 163840; break;
    case 4: src = W_f1 + (size_t)layer * 262144; K = 256;  N = 1024; dof = 229376; break;
    default:src = W_f2 + (size_t)layer * 262144; K = 1024; N = 256;  dof = 491520; break;
  }
  int Kt = K >> 6;
  int k0 = (ti % Kt) * 64, n0 = (ti / Kt) * 64;
  ushort_t* dst = wt + (size_t)layer * 753664 + dof;
  int t = threadIdx.x;
  int rr = t >> 2, c4 = (t & 3) * 16;
  #pragma unroll
  for (int i = 0; i < 4; ++i) {
    f32x4 v = *(const f32x4*)(src + (size_t)(k0 + rr) * N + n0 + c4 + i * 4);
    tile[c4 + i*4 + 0][rr] = v[0];
    tile[c4 + i*4 + 1][rr] = v[1];
    tile[c4 + i*4 + 2][rr] = v[2];
    tile[c4 + i*4 + 3][rr] = v[3];
  }
  __syncthreads();
  #pragma unroll
  for (int i = 0; i < 4; ++i) {
    u16x4 o;
    #pragma unroll
    for (int j = 0; j < 4; ++j) o[j] = f2b(tile[rr][c4 + i*4 + j]);
    *(u16x4*)(dst + (size_t)(n0 + rr) * K + k0 + c4 + i * 4) = o;
  }
}

__global__ void bias_fuse(const float* __restrict__ bso,
                          const float* __restrict__ baw,
                          float* __restrict__ bsa)
{
  int l = blockIdx.x, t = threadIdx.x;
  bsa[l * 384 + t] = (t < 256) ? bso[l * 256 + t] : baw[l * 128 + t - 256];
}

// ---------------------------------------------------------------------------
// Shared 128x128 MFMA GEMM body (BK=64, 4 waves, swizzled LDS).
__device__ __forceinline__ void gemm_body(
    ushort_t* As, ushort_t* Bs,
    const ushort_t* __restrict__ A, const ushort_t* __restrict__ Bt,
    const float* __restrict__ bias, ushort_t* __restrict__ Cb,
    int N, int n0, int m0, int K, int relu)
{
  int t = threadIdx.x;
  int l = t & 63, w = t >> 6;
  int wr = w >> 1, wc = w & 1;
  int lq = l >> 4, l15 = l & 15, r7 = l & 7;
  f32x4 acc[4][4] = {};

  for (int k0 = 0; k0 < K; k0 += 64) {
    #pragma unroll
    for (int i = 0; i < 4; ++i) {
      int c = i * 256 + t;
      int row = c >> 3;
      int sc = (c & 7) ^ (row & 7);
      __builtin_amdgcn_global_load_lds(
          (const uint32_t*)(A + (size_t)(m0 + row) * K + k0 + sc * 8),
          (uint32_t*)((char*)As + c * 16), 16, 0, 0);
      __builtin_amdgcn_global_load_lds(
          (const uint32_t*)(Bt + (size_t)(n0 + row) * K + k0 + sc * 8),
          (uint32_t*)((char*)Bs + c * 16), 16, 0, 0);
    }
    __syncthreads();
    #pragma unroll
    for (int ks = 0; ks < 2; ++ks) {
      bf16x8 af[4], bfr[4];
      int chs = ((ks << 2) + lq) ^ r7;
      #pragma unroll
      for (int mt = 0; mt < 4; ++mt)
        af[mt] = *(const bf16x8*)((const char*)As +
                   (wr * 64 + mt * 16 + l15) * 128 + (chs << 4));
      #pragma unroll
      for (int nt = 0; nt < 4; ++nt)
        bfr[nt] = *(const bf16x8*)((const char*)Bs +
                   (wc * 64 + nt * 16 + l15) * 128 + (chs << 4));
      #pragma unroll
      for (int mt = 0; mt < 4; ++mt)
        #pragma unroll
        for (int nt = 0; nt < 4; ++nt)
          acc[mt][nt] = __builtin_amdgcn_mfma_f32_16x16x32_bf16(
              af[mt], bfr[nt], acc[mt][nt], 0, 0, 0);
    }
    __syncthreads();
  }

  int crow0 = m0 + wr * 64;
  int ccol0 = n0 + wc * 64;
  #pragma unroll
  for (int mt = 0; mt < 4; ++mt) {
    #pragma unroll
    for (int nt = 0; nt < 4; ++nt) {
      int col = ccol0 + nt * 16 + l15;
      float bv = bias[col];
      #pragma unroll
      for (int r = 0; r < 4; ++r) {
        int rowg = crow0 + mt * 16 + lq * 4 + r;
        float v = acc[mt][nt][r] + bv;
        if (relu) v = fmaxf(v, 0.f);
        Cb[(size_t)rowg * N + col] = f2b(v);
      }
    }
  }
}

// FFN1 GEMM (relu)
__global__ __launch_bounds__(256) void gemm_mfma(
    const ushort_t* __restrict__ A, const ushort_t* __restrict__ Bt,
    const float* __restrict__ bias, ushort_t* __restrict__ Cb,
    int N, int K, int relu)
{
  __shared__ alignas(16) ushort_t As[8192];
  __shared__ alignas(16) ushort_t Bs[8192];
  gemm_body(As, Bs, A, Bt, bias, Cb, N, blockIdx.y * 128, blockIdx.x * 128, K, relu);
}

// Merged sa(q@Wsa, N=384) + val(cur@Wv, N=256) dispatch: grid.y = 0..4
__global__ __launch_bounds__(256) void gemm_dual(
    const ushort_t* __restrict__ A0, const ushort_t* __restrict__ Bt0,
    const float* __restrict__ bias0, ushort_t* __restrict__ C0,
    const ushort_t* __restrict__ A1, const ushort_t* __restrict__ Bt1,
    const float* __restrict__ bias1, ushort_t* __restrict__ C1,
    int K)
{
  __shared__ alignas(16) ushort_t As[8192];
  __shared__ alignas(16) ushort_t Bs[8192];
  int gy = blockIdx.y;
  if (gy < 3)
    gemm_body(As, Bs, A0, Bt0, bias0, C0, 384, gy * 128, blockIdx.x * 128, K, 0);
  else
    gemm_body(As, Bs, A1, Bt1, bias1, C1, 256, (gy - 3) * 128, blockIdx.x * 128, K, 0);
}

// ---------------------------------------------------------------------------
// Fused GEMM (N=256) + residual + LayerNorm. Tile 64x256, 4 waves (256 thr).
__global__ __launch_bounds__(256) void gemm_ln(
    const ushort_t* __restrict__ A, const ushort_t* __restrict__ Bt,
    const float* __restrict__ bias, const float* __restrict__ res,
    const float* __restrict__ g, const float* __restrict__ be,
    float* __restrict__ Of, ushort_t* __restrict__ Ob,
    ushort_t* __restrict__ Oq, const ushort_t* __restrict__ posb,
    int K)
{
  __shared__ alignas(16) ushort_t As[64 * 64];    // 8 KB
  __shared__ alignas(16) ushort_t Bs[256 * 64];   // 32 KB
  __shared__ float psum[64][4];
  __shared__ float psum2[64][4];
  __shared__ float2 mstd[64];
  int t = threadIdx.x;
  int l = t & 63, w = t >> 6;          // w = column-span 0..3
  int m0 = blockIdx.x * 64;
  int lq = l >> 4, l15 = l & 15, r7 = l & 7;
  f32x4 acc[4][4] = {};

  for (int k0 = 0; k0 < K; k0 += 64) {
    #pragma unroll
    for (int i = 0; i < 2; ++i) {          // A: 512 chunks
      int c = i * 256 + t;
      int row = c >> 3;
      int sc = (c & 7) ^ (row & 7);
      __builtin_amdgcn_global_load_lds(
          (const uint32_t*)(A + (size_t)(m0 + row) * K + k0 + sc * 8),
          (uint32_t*)((char*)As + c * 16), 16, 0, 0);
    }
    #pragma unroll
    for (int i = 0; i < 8; ++i) {          // B: 2048 chunks
      int c = i * 256 + t;
      int row = c >> 3;
      int sc = (c & 7) ^ (row & 7);
      __builtin_amdgcn_global_load_lds(
          (const uint32_t*)(Bt + (size_t)row * K + k0 + sc * 8),
          (uint32_t*)((char*)Bs + c * 16), 16, 0, 0);
    }
    __syncthreads();
    #pragma unroll
    for (int ks = 0; ks < 2; ++ks) {
      bf16x8 af[4], bfr[4];
      int chs = ((ks << 2) + lq) ^ r7;
      #pragma unroll
      for (int mt = 0; mt < 4; ++mt)
        af[mt] = *(const bf16x8*)((const char*)As +
                   (mt * 16 + l15) * 128 + (chs << 4));
      #pragma unroll
      for (int nt = 0; nt < 4; ++nt)
        bfr[nt] = *(const bf16x8*)((const char*)Bs +
                   (w * 64 + nt * 16 + l15) * 128 + (chs << 4));
      #pragma unroll
      for (int mt = 0; mt < 4; ++mt)
        #pragma unroll
        for (int nt = 0; nt < 4; ++nt)
          acc[mt][nt] = __builtin_amdgcn_mfma_f32_16x16x32_bf16(
              af[mt], bfr[nt], acc[mt][nt], 0, 0, 0);
    }
    __syncthreads();
  }

  // epilogue: bias + residual, LN over 256-wide rows
  float gv[4], bev[4], biasv[4];
  #pragma unroll
  for (int nt = 0; nt < 4; ++nt) {
    int col = w * 64 + nt * 16 + l15;
    gv[nt] = g[col]; bev[nt] = be[col]; biasv[nt] = bias[col];
  }
  #pragma unroll
  for (int mt = 0; mt < 4; ++mt) {
    #pragma unroll
    for (int r = 0; r < 4; ++r) {
      int rowg = m0 + mt * 16 + lq * 4 + r;
      #pragma unroll
      for (int nt = 0; nt < 4; ++nt) {
        int col = w * 64 + nt * 16 + l15;
        acc[mt][nt][r] += biasv[nt] + res[(size_t)rowg * 256 + col];
      }
    }
  }
  #pragma unroll
  for (int mt = 0; mt < 4; ++mt) {
    #pragma unroll
    for (int r = 0; r < 4; ++r) {
      float s = 0.f, s2 = 0.f;
      #pragma unroll
      for (int nt = 0; nt < 4; ++nt) {
        float v = acc[mt][nt][r];
        s += v; s2 += v * v;
      }
      #pragma unroll
      for (int off = 1; off < 16; off <<= 1) {
        s  += __shfl_xor(s, off);
        s2 += __shfl_xor(s2, off);
      }
      if (l15 == 0) {
        int rloc = mt * 16 + lq * 4 + r;
        psum[rloc][w] = s;
        psum2[rloc][w] = s2;
      }
    }
  }
  __syncthreads();
  if (t < 64) {
    f32x4 a = *(const f32x4*)psum[t];
    f32x4 b = *(const f32x4*)psum2[t];
    float s = a[0] + a[1] + a[2] + a[3];
    float s2 = b[0] + b[1] + b[2] + b[3];
    float mean = s * (1.f / 256.f);
    float var = s2 * (1.f / 256.f) - mean * mean;
    mstd[t] = make_float2(mean, rsqrtf(var + 1e-5f));
  }
  __syncthreads();
  #pragma unroll
  for (int mt = 0; mt < 4; ++mt) {
    #pragma unroll
    for (int r = 0; r < 4; ++r) {
      int rloc = mt * 16 + lq * 4 + r;
      int rowg = m0 + rloc;
      float2 ms = mstd[rloc];
      #pragma unroll
      for (int nt = 0; nt < 4; ++nt) {
        int col = w * 64 + nt * 16 + l15;
        float y = (acc[mt][nt][r] - ms.x) * ms.y * gv[nt] + bev[nt];
        size_t o = (size_t)rowg * 256 + col;
        Of[o] = y;
        Ob[o] = f2b(y);
        if (Oq) Oq[o] = f2b(y + b2f(posb[o]));
      }
    }
  }
}

// ---------------------------------------------------------------------------
// Deformable sampling v4: 4 tokens/block, 64 thr/token, 4 channels/thread.
// Padded LDS (pi = pt + pt>>4) -> conflict-free b128 reads.
__global__ __launch_bounds__(256) void sample_kernel(
    const ushort_t* __restrict__ val, const ushort_t* __restrict__ sa,
    ushort_t* __restrict__ att)
{
  __shared__ int4   sIdx4[4][136];
  __shared__ float4 sW4[4][136];
  int tid = threadIdx.x;
  int t0 = blockIdx.x * 4;
  int u = tid & 127;

  #pragma unroll
  for (int it = 0; it < 2; ++it) {
    int tl = (tid >> 7) * 2 + it;
    int t = t0 + tl;
    int b = t / SSn, s = t % SSn;
    int pt = u;
    int lvl = (pt >> 2) & 3;
    int st, Wt;
    if (s < 4096)      { st = 0;    Wt = 64; }
    else if (s < 5120) { st = 4096; Wt = 32; }
    else if (s < 5376) { st = 5120; Wt = 16; }
    else               { st = 5376; Wt = 8;  }
    int p = s - st;
    int iy = p / Wt, ix = p % Wt;
    float refx = (ix + 0.5f) / Wt;
    float refy = (iy + 0.5f) / Wt;

    float logit = b2f(sa[(size_t)t * 384 + 256 + pt]);
    float m = logit;
    #pragma unroll
    for (int off = 1; off < 16; off <<= 1) m = fmaxf(m, __shfl_xor(m, off));
    float e = __expf(logit - m);
    float sum = e;
    #pragma unroll
    for (int off = 1; off < 16; off <<= 1) sum += __shfl_xor(sum, off);
    float wa = e / sum;

    const int LWt[4] = {64, 32, 16, 8};
    const int LST[4] = {0, 4096, 5120, 5376};
    int Wl = LWt[lvl], Hl = Wl, stl = LST[lvl];

    float ox = b2f(sa[(size_t)t * 384 + pt * 2]);
    float oy = b2f(sa[(size_t)t * 384 + pt * 2 + 1]);
    float x = refx * Wl + ox - 0.5f;
    float y = refy * Hl + oy - 0.5f;
    float x0f = floorf(x), y0f = floorf(y);
    int x0 = (int)x0f, y0 = (int)y0f;
    float wx1 = x - x0f, wy1 = y - y0f;
    int vbase = b * SSn + stl;
    int4 idx4; float4 w4;
    int* ip = (int*)&idx4; float* wp = (float*)&w4;
    #pragma unroll
    for (int c = 0; c < 4; ++c) {
      int dx = c & 1, dy = c >> 1;
      int xi = x0 + dx, yi = y0 + dy;
      float wgt = (dx ? wx1 : 1.f - wx1) * (dy ? wy1 : 1.f - wy1);
      bool valid = (xi >= 0) & (xi < Wl) & (yi >= 0) & (yi < Hl);
      int xc = min(max(xi, 0), Wl - 1), yc = min(max(yi, 0), Hl - 1);
      ip[c] = vbase + yc * Wl + xc;
      wp[c] = valid ? wgt * wa : 0.f;
    }
    int pi = pt + (pt >> 4);
    sIdx4[tl][pi] = idx4;
    sW4[tl][pi] = w4;
  }
  __syncthreads();

  int tl = tid >> 6, v = tid & 63;
  int t = t0 + tl;
  int h = v >> 3, j = v & 7;
  int c0 = h * 32 + j * 4;
  float a0 = 0.f, a1 = 0.f, a2 = 0.f, a3 = 0.f;
  #pragma unroll
  for (int k = 0; k < 16; ++k) {
    int pt = h * 16 + k;
    int pi = pt + (pt >> 4);
    int4 idx4 = sIdx4[tl][pi];
    float4 w4 = sW4[tl][pi];
    const int* ip = (const int*)&idx4;
    const float* wp = (const float*)&w4;
    #pragma unroll
    for (int c = 0; c < 4; ++c) {
      uint2 uv = *(const uint2*)(val + ((size_t)ip[c] << 8) + c0);
      float wv = wp[c];
      a0 += wv * __uint_as_float(uv.x << 16);
      a1 += wv * __uint_as_float(uv.x & 0xFFFF0000u);
      a2 += wv * __uint_as_float(uv.y << 16);
      a3 += wv * __uint_as_float(uv.y & 0xFFFF0000u);
    }
  }
  uint2 pk;
  pk.x = (uint32_t)f2b(a0) | ((uint32_t)f2b(a1) << 16);
  pk.y = (uint32_t)f2b(a2) | ((uint32_t)f2b(a3) << 16);
  *(uint2*)(att + (size_t)t * 256 + c0) = pk;
}

// ---------------------------------------------------------------------------
__global__ void tail_kernel(float* __restrict__ o) {
  const float v[12] = {64.f, 64.f, 32.f, 32.f, 16.f, 16.f, 8.f, 8.f,
                       0.f, 4096.f, 5120.f, 5376.f};
  int i = threadIdx.x;
  if (i < 12) o[i] = v[i];
}

// ---------------------------------------------------------------------------
extern "C" void kernel_launch(void* const* d_in, const int* in_sizes, int n_in,
                              void* d_out, int out_size, void* d_ws, size_t ws_size,
                              hipStream_t stream)
{
  const float* s0  = (const float*)d_in[0];
  const float* p0  = (const float*)d_in[1];
  const float* s1  = (const float*)d_in[2];
  const float* p1  = (const float*)d_in[3];
  const float* s2  = (const float*)d_in[4];
  const float* p2  = (const float*)d_in[5];
  const float* s3  = (const float*)d_in[6];
  const float* p3  = (const float*)d_in[7];
  const float* lev = (const float*)d_in[8];
  const float* W_so = (const float*)d_in[9];
  const float* b_so = (const float*)d_in[10];
  const float* W_aw = (const float*)d_in[11];
  const float* b_aw = (const float*)d_in[12];
  const float* W_v  = (const float*)d_in[13];
  const float* b_v  = (const float*)d_in[14];
  const float* W_o  = (const float*)d_in[15];
  const float* b_o  = (const float*)d_in[16];
  const float* g1   = (const float*)d_in[17];
  const float* be1  = (const float*)d_in[18];
  const float* W_f1 = (const float*)d_in[19];
  const float* b_f1 = (const float*)d_in[20];
  const float* W_f2 = (const float*)d_in[21];
  const float* b_f2 = (const float*)d_in[22];
  const float* g2   = (const float*)d_in[23];
  const float* be2  = (const float*)d_in[24];

  float* out = (float*)d_out;
  float* ws  = (float*)d_ws;

  // workspace layout (f32 units). Total ~5.41 TD = 120.5 MB.
  ushort_t* pos_b = (ushort_t*)ws;                          // 0.5 TD
  float*    x_f   = ws + TD / 2;                            // 1 TD
  ushort_t* q_b   = (ushort_t*)(ws + TD / 2 + TD);          // 0.5 TD (q / att)
  ushort_t* cur_b = (ushort_t*)(ws + 2 * TD);               // 0.5 TD
  ushort_t* x_b   = (ushort_t*)(ws + 2 * TD + TD / 2);      // 0.5 TD
  // H region: 2 TD. Phase1: sa_b (0.75 TD) + val_b (0.5 TD). Phase3: h_b (2 TD).
  ushort_t* sa_b  = (ushort_t*)(ws + 3 * TD);
  ushort_t* val_b = (ushort_t*)(ws + 3 * TD + 3 * (TD / 4));
  ushort_t* h_b   = (ushort_t*)(ws + 3 * TD);
  ushort_t* wt    = (ushort_t*)(ws + 5 * TD);               // 4,521,984 bf16
  float*    bsa   = ws + 5 * TD + 2260992;                  // 6*384 f32

  const size_t LW = 753664;  // per-layer transposed-weight stride (bf16)

  wprep_kernel<<<1104, 256, 0, stream>>>(W_so, W_aw, W_v, W_o, W_f1, W_f2, wt);
  bias_fuse<<<NL, 384, 0, stream>>>(b_so, b_aw, bsa);
  prep_kernel<<<1360, 256, 0, stream>>>(s0, p0, s1, p1, s2, p2, s3, p3, lev,
                                        out, cur_b, pos_b, q_b);

  for (int i = 0; i < NL; ++i) {
    ushort_t* wl = wt + (size_t)i * LW;
    const float* bv  = b_v  + (size_t)i * 256;
    const float* bo  = b_o  + (size_t)i * 256;
    const float* bf1 = b_f1 + (size_t)i * 1024;
    const float* bf2 = b_f2 + (size_t)i * 256;

    // merged: sa = q@Wsa (N=384) and val = cur@Wv (N=256)
    gemm_dual<<<dim3(170, 5), 256, 0, stream>>>(q_b, wl + 0, bsa + i * 384, sa_b,
                                                cur_b, wl + 98304, bv, val_b, 256);
    // deformable sampling -> att (bf16, overwrites q_b)
    sample_kernel<<<TTn / 4, 256, 0, stream>>>(val_b, sa_b, q_b);
    // Wo projection + residual(cur f32) + LN1 -> x_f, x_b
    gemm_ln<<<340, 256, 0, stream>>>(q_b, wl + 163840, bo, out,
                                     g1 + i * 256, be1 + i * 256,
                                     x_f, x_b, nullptr, nullptr, 256);
    // FFN1 (relu) -> h_b
    gemm_mfma<<<dim3(170, 8), 256, 0, stream>>>(x_b, wl + 229376, bf1,
                                                h_b, 1024, 256, 1);
    // FFN2 + residual(x_f) + LN2 -> out (f32), cur_b, q_b(next = y+pos)
    gemm_ln<<<340, 256, 0, stream>>>(h_b, wl + 491520, bf2, x_f,
                                     g2 + i * 256, be2 + i * 256,
                                     out, cur_b, q_b, pos_b, 1024);
  }

  tail_kernel<<<1, 16, 0, stream>>>(out + TD);
}

// Round 5
// 805.645 us; speedup vs baseline: 6.0098x; 1.1823x over previous
//
#include <hip/hip_runtime.h>
#include <cstdint>

#define SSn 5440
#define TTn 21760
#define TD ((size_t)TTn*256)
#define NL 6

typedef short bf16x8 __attribute__((ext_vector_type(8)));
typedef float f32x4 __attribute__((ext_vector_type(4)));
typedef unsigned short u16x4 __attribute__((ext_vector_type(4)));
typedef unsigned short ushort_t;

__device__ __forceinline__ ushort_t f2b(float f) {
  uint32_t x = __float_as_uint(f);
  uint32_t r = x + 0x7FFFu + ((x >> 16) & 1u);
  return (ushort_t)(r >> 16);
}
__device__ __forceinline__ float b2f(ushort_t u) {
  return __uint_as_float((uint32_t)u << 16);
}

// ---------------------------------------------------------------------------
// Preprocess: tiled 64x64 LDS transpose. 340 tiles/batch x 4 = 1360 blocks.
__global__ __launch_bounds__(256) void prep_kernel(
    const float* __restrict__ s0, const float* __restrict__ p0,
    const float* __restrict__ s1, const float* __restrict__ p1,
    const float* __restrict__ s2, const float* __restrict__ p2,
    const float* __restrict__ s3, const float* __restrict__ p3,
    const float* __restrict__ lev,
    float* __restrict__ cur, ushort_t* __restrict__ cur_b,
    ushort_t* __restrict__ pos_b, ushort_t* __restrict__ q_b)
{
  __shared__ float ts[64][65];
  __shared__ float tp[64][65];
  int bx = blockIdx.x;
  int b = bx / 340, r = bx % 340;
  const float *sp, *pp; int l, HW, start, dt, ptile;
  if (r < 256)      { l=0; HW=4096; start=0;    sp=s0; pp=p0; dt=r>>6;       ptile=r&63; }
  else if (r < 320) { l=1; HW=1024; start=4096; sp=s1; pp=p1; dt=(r-256)>>4; ptile=(r-256)&15; }
  else if (r < 336) { l=2; HW=256;  start=5120; sp=s2; pp=p2; dt=(r-320)>>2; ptile=(r-320)&3; }
  else              { l=3; HW=64;   start=5376; sp=s3; pp=p3; dt=r-336;      ptile=0; }
  int d0 = dt * 64, pp0 = ptile * 64;
  int t = threadIdx.x;
  int rr = t >> 2, c4 = (t & 3) * 16;
  size_t ibase = ((size_t)b * 256 + d0 + rr) * HW + pp0;
  #pragma unroll
  for (int i = 0; i < 4; ++i) {
    f32x4 v = *(const f32x4*)(sp + ibase + c4 + i * 4);
    f32x4 w = *(const f32x4*)(pp + ibase + c4 + i * 4);
    #pragma unroll
    for (int j = 0; j < 4; ++j) { ts[c4 + i*4 + j][rr] = v[j]; tp[c4 + i*4 + j][rr] = w[j]; }
  }
  __syncthreads();
  int token = start + pp0 + rr;
  size_t obase = ((size_t)b * SSn + token) * 256 + d0;
  #pragma unroll
  for (int i = 0; i < 4; ++i) {
    f32x4 cv; u16x4 cb, pb, qb;
    #pragma unroll
    for (int j = 0; j < 4; ++j) {
      float c = ts[rr][c4 + i*4 + j];
      float p = tp[rr][c4 + i*4 + j] + lev[l * 256 + d0 + c4 + i*4 + j];
      cv[j] = c; cb[j] = f2b(c); pb[j] = f2b(p); qb[j] = f2b(c + p);
    }
    *(f32x4*)(cur + obase + c4 + i*4) = cv;
    *(u16x4*)(cur_b + obase + c4 + i*4) = cb;
    *(u16x4*)(pos_b + obase + c4 + i*4) = pb;
    *(u16x4*)(q_b + obase + c4 + i*4) = qb;
  }
}

// ---------------------------------------------------------------------------
// Batched weight transpose+convert (unchanged)
__global__ __launch_bounds__(256) void wprep_kernel(
    const float* __restrict__ W_so, const float* __restrict__ W_aw,
    const float* __restrict__ W_v,  const float* __restrict__ W_o,
    const float* __restrict__ W_f1, const float* __restrict__ W_f2,
    ushort_t* __restrict__ wt)
{
  __shared__ float tile[64][65];
  int bx = blockIdx.x;
  int layer = bx / 184, r = bx % 184;
  int type, ti;
  if (r < 16)       { type = 0; ti = r; }
  else if (r < 24)  { type = 1; ti = r - 16; }
  else if (r < 40)  { type = 2; ti = r - 24; }
  else if (r < 56)  { type = 3; ti = r - 40; }
  else if (r < 120) { type = 4; ti = r - 56; }
  else              { type = 5; ti = r - 120; }
  const float* src;
  int K, N, dof;
  switch (type) {
    case 0: src = W_so + (size_t)layer * 65536;  K = 256;  N = 256;  dof = 0;      break;
    case 1: src = W_aw + (size_t)layer * 32768;  K = 256;  N = 128;  dof = 65536;  break;
    case 2: src = W_v  + (size_t)layer * 65536;  K = 256;  N = 256;  dof = 98304;  break;
    case 3: src = W_o  + (size_t)layer * 65536;  K = 256;  N = 256;  dof = 163840; break;
    case 4: src = W_f1 + (size_t)layer * 262144; K = 256;  N = 1024; dof = 229376; break;
    default:src = W_f2 + (size_t)layer * 262144; K = 1024; N = 256;  dof = 491520; break;
  }
  int Kt = K >> 6;
  int k0 = (ti % Kt) * 64, n0 = (ti / Kt) * 64;
  ushort_t* dst = wt + (size_t)layer * 753664 + dof;
  int t = threadIdx.x;
  int rr = t >> 2, c4 = (t & 3) * 16;
  #pragma unroll
  for (int i = 0; i < 4; ++i) {
    f32x4 v = *(const f32x4*)(src + (size_t)(k0 + rr) * N + n0 + c4 + i * 4);
    tile[c4 + i*4 + 0][rr] = v[0];
    tile[c4 + i*4 + 1][rr] = v[1];
    tile[c4 + i*4 + 2][rr] = v[2];
    tile[c4 + i*4 + 3][rr] = v[3];
  }
  __syncthreads();
  #pragma unroll
  for (int i = 0; i < 4; ++i) {
    u16x4 o;
    #pragma unroll
    for (int j = 0; j < 4; ++j) o[j] = f2b(tile[rr][c4 + i*4 + j]);
    *(u16x4*)(dst + (size_t)(n0 + rr) * K + k0 + c4 + i * 4) = o;
  }
}

__global__ void bias_fuse(const float* __restrict__ bso,
                          const float* __restrict__ baw,
                          float* __restrict__ bsa)
{
  int l = blockIdx.x, t = threadIdx.x;
  bsa[l * 384 + t] = (t < 256) ? bso[l * 256 + t] : baw[l * 128 + t - 256];
}

// ---------------------------------------------------------------------------
// Shared 128x128 MFMA GEMM body (BK=64, 4 waves, swizzled LDS).
__device__ __forceinline__ void gemm_body(
    ushort_t* As, ushort_t* Bs,
    const ushort_t* __restrict__ A, const ushort_t* __restrict__ Bt,
    const float* __restrict__ bias, ushort_t* __restrict__ Cb,
    int N, int n0, int m0, int K, int relu)
{
  int t = threadIdx.x;
  int l = t & 63, w = t >> 6;
  int wr = w >> 1, wc = w & 1;
  int lq = l >> 4, l15 = l & 15, r7 = l & 7;
  f32x4 acc[4][4] = {};

  for (int k0 = 0; k0 < K; k0 += 64) {
    #pragma unroll
    for (int i = 0; i < 4; ++i) {
      int c = i * 256 + t;
      int row = c >> 3;
      int sc = (c & 7) ^ (row & 7);
      __builtin_amdgcn_global_load_lds(
          (const uint32_t*)(A + (size_t)(m0 + row) * K + k0 + sc * 8),
          (uint32_t*)((char*)As + c * 16), 16, 0, 0);
      __builtin_amdgcn_global_load_lds(
          (const uint32_t*)(Bt + (size_t)(n0 + row) * K + k0 + sc * 8),
          (uint32_t*)((char*)Bs + c * 16), 16, 0, 0);
    }
    __syncthreads();
    #pragma unroll
    for (int ks = 0; ks < 2; ++ks) {
      bf16x8 af[4], bfr[4];
      int chs = ((ks << 2) + lq) ^ r7;
      #pragma unroll
      for (int mt = 0; mt < 4; ++mt)
        af[mt] = *(const bf16x8*)((const char*)As +
                   (wr * 64 + mt * 16 + l15) * 128 + (chs << 4));
      #pragma unroll
      for (int nt = 0; nt < 4; ++nt)
        bfr[nt] = *(const bf16x8*)((const char*)Bs +
                   (wc * 64 + nt * 16 + l15) * 128 + (chs << 4));
      #pragma unroll
      for (int mt = 0; mt < 4; ++mt)
        #pragma unroll
        for (int nt = 0; nt < 4; ++nt)
          acc[mt][nt] = __builtin_amdgcn_mfma_f32_16x16x32_bf16(
              af[mt], bfr[nt], acc[mt][nt], 0, 0, 0);
    }
    __syncthreads();
  }

  int crow0 = m0 + wr * 64;
  int ccol0 = n0 + wc * 64;
  #pragma unroll
  for (int mt = 0; mt < 4; ++mt) {
    #pragma unroll
    for (int nt = 0; nt < 4; ++nt) {
      int col = ccol0 + nt * 16 + l15;
      float bv = bias[col];
      #pragma unroll
      for (int r = 0; r < 4; ++r) {
        int rowg = crow0 + mt * 16 + lq * 4 + r;
        float v = acc[mt][nt][r] + bv;
        if (relu) v = fmaxf(v, 0.f);
        Cb[(size_t)rowg * N + col] = f2b(v);
      }
    }
  }
}

// FFN1 GEMM (relu)
__global__ __launch_bounds__(256) void gemm_mfma(
    const ushort_t* __restrict__ A, const ushort_t* __restrict__ Bt,
    const float* __restrict__ bias, ushort_t* __restrict__ Cb,
    int N, int K, int relu)
{
  __shared__ alignas(16) ushort_t As[8192];
  __shared__ alignas(16) ushort_t Bs[8192];
  gemm_body(As, Bs, A, Bt, bias, Cb, N, blockIdx.y * 128, blockIdx.x * 128, K, relu);
}

// Merged sa(q@Wsa, N=384) + val(cur@Wv, N=256) dispatch: grid.y = 0..4
__global__ __launch_bounds__(256) void gemm_dual(
    const ushort_t* __restrict__ A0, const ushort_t* __restrict__ Bt0,
    const float* __restrict__ bias0, ushort_t* __restrict__ C0,
    const ushort_t* __restrict__ A1, const ushort_t* __restrict__ Bt1,
    const float* __restrict__ bias1, ushort_t* __restrict__ C1,
    int K)
{
  __shared__ alignas(16) ushort_t As[8192];
  __shared__ alignas(16) ushort_t Bs[8192];
  int gy = blockIdx.y;
  if (gy < 3)
    gemm_body(As, Bs, A0, Bt0, bias0, C0, 384, gy * 128, blockIdx.x * 128, K, 0);
  else
    gemm_body(As, Bs, A1, Bt1, bias1, C1, 256, (gy - 3) * 128, blockIdx.x * 128, K, 0);
}

// ---------------------------------------------------------------------------
// Fused GEMM (N=256) + residual + LayerNorm. Tile 32x256, 4 waves (256 thr).
// Grid = TTn/32 = 680 blocks -> ~10.6 waves/CU resident (vs 5 at 64-row).
__global__ __launch_bounds__(256) void gemm_ln(
    const ushort_t* __restrict__ A, const ushort_t* __restrict__ Bt,
    const float* __restrict__ bias, const float* __restrict__ res,
    const float* __restrict__ g, const float* __restrict__ be,
    float* __restrict__ Of, ushort_t* __restrict__ Ob,
    ushort_t* __restrict__ Oq, const ushort_t* __restrict__ posb,
    int K)
{
  __shared__ alignas(16) ushort_t As[32 * 64];    // 4 KB
  __shared__ alignas(16) ushort_t Bs[256 * 64];   // 32 KB
  __shared__ float psum[32][4];
  __shared__ float psum2[32][4];
  __shared__ float2 mstd[32];
  int t = threadIdx.x;
  int l = t & 63, w = t >> 6;          // w = column-span 0..3
  int m0 = blockIdx.x * 32;
  int lq = l >> 4, l15 = l & 15, r7 = l & 7;
  f32x4 acc[2][4] = {};

  for (int k0 = 0; k0 < K; k0 += 64) {
    {                                       // A: 256 chunks, 1/thread
      int c = t;
      int row = c >> 3;
      int sc = (c & 7) ^ (row & 7);
      __builtin_amdgcn_global_load_lds(
          (const uint32_t*)(A + (size_t)(m0 + row) * K + k0 + sc * 8),
          (uint32_t*)((char*)As + c * 16), 16, 0, 0);
    }
    #pragma unroll
    for (int i = 0; i < 8; ++i) {           // B: 2048 chunks
      int c = i * 256 + t;
      int row = c >> 3;
      int sc = (c & 7) ^ (row & 7);
      __builtin_amdgcn_global_load_lds(
          (const uint32_t*)(Bt + (size_t)row * K + k0 + sc * 8),
          (uint32_t*)((char*)Bs + c * 16), 16, 0, 0);
    }
    __syncthreads();
    #pragma unroll
    for (int ks = 0; ks < 2; ++ks) {
      bf16x8 af[2], bfr[4];
      int chs = ((ks << 2) + lq) ^ r7;
      #pragma unroll
      for (int mt = 0; mt < 2; ++mt)
        af[mt] = *(const bf16x8*)((const char*)As +
                   (mt * 16 + l15) * 128 + (chs << 4));
      #pragma unroll
      for (int nt = 0; nt < 4; ++nt)
        bfr[nt] = *(const bf16x8*)((const char*)Bs +
                   (w * 64 + nt * 16 + l15) * 128 + (chs << 4));
      #pragma unroll
      for (int mt = 0; mt < 2; ++mt)
        #pragma unroll
        for (int nt = 0; nt < 4; ++nt)
          acc[mt][nt] = __builtin_amdgcn_mfma_f32_16x16x32_bf16(
              af[mt], bfr[nt], acc[mt][nt], 0, 0, 0);
    }
    __syncthreads();
  }

  // epilogue: bias + residual, LN over 256-wide rows
  float gv[4], bev[4], biasv[4];
  #pragma unroll
  for (int nt = 0; nt < 4; ++nt) {
    int col = w * 64 + nt * 16 + l15;
    gv[nt] = g[col]; bev[nt] = be[col]; biasv[nt] = bias[col];
  }
  #pragma unroll
  for (int mt = 0; mt < 2; ++mt) {
    #pragma unroll
    for (int r = 0; r < 4; ++r) {
      int rowg = m0 + mt * 16 + lq * 4 + r;
      #pragma unroll
      for (int nt = 0; nt < 4; ++nt) {
        int col = w * 64 + nt * 16 + l15;
        acc[mt][nt][r] += biasv[nt] + res[(size_t)rowg * 256 + col];
      }
    }
  }
  #pragma unroll
  for (int mt = 0; mt < 2; ++mt) {
    #pragma unroll
    for (int r = 0; r < 4; ++r) {
      float s = 0.f, s2 = 0.f;
      #pragma unroll
      for (int nt = 0; nt < 4; ++nt) {
        float v = acc[mt][nt][r];
        s += v; s2 += v * v;
      }
      #pragma unroll
      for (int off = 1; off < 16; off <<= 1) {
        s  += __shfl_xor(s, off);
        s2 += __shfl_xor(s2, off);
      }
      if (l15 == 0) {
        int rloc = mt * 16 + lq * 4 + r;
        psum[rloc][w] = s;
        psum2[rloc][w] = s2;
      }
    }
  }
  __syncthreads();
  if (t < 32) {
    f32x4 a = *(const f32x4*)psum[t];
    f32x4 b = *(const f32x4*)psum2[t];
    float s = a[0] + a[1] + a[2] + a[3];
    float s2 = b[0] + b[1] + b[2] + b[3];
    float mean = s * (1.f / 256.f);
    float var = s2 * (1.f / 256.f) - mean * mean;
    mstd[t] = make_float2(mean, rsqrtf(var + 1e-5f));
  }
  __syncthreads();
  #pragma unroll
  for (int mt = 0; mt < 2; ++mt) {
    #pragma unroll
    for (int r = 0; r < 4; ++r) {
      int rloc = mt * 16 + lq * 4 + r;
      int rowg = m0 + rloc;
      float2 ms = mstd[rloc];
      #pragma unroll
      for (int nt = 0; nt < 4; ++nt) {
        int col = w * 64 + nt * 16 + l15;
        float y = (acc[mt][nt][r] - ms.x) * ms.y * gv[nt] + bev[nt];
        size_t o = (size_t)rowg * 256 + col;
        Of[o] = y;
        Ob[o] = f2b(y);
        if (Oq) Oq[o] = f2b(y + b2f(posb[o]));
      }
    }
  }
}

// ---------------------------------------------------------------------------
// Deformable sampling v5: 8 tokens/block, 32 thr/token, 8 channels/thread,
// uint4 (16B) gathers. Padded LDS (pi = h*17 + k) keeps b128 reads <=2-way.
__global__ __launch_bounds__(256) void sample_kernel(
    const ushort_t* __restrict__ val, const ushort_t* __restrict__ sa,
    ushort_t* __restrict__ att)
{
  __shared__ int4   sIdx4[8][136];
  __shared__ float4 sW4[8][136];
  int tid = threadIdx.x;
  int t0 = blockIdx.x * 8;

  #pragma unroll
  for (int it = 0; it < 4; ++it) {
    int idx = it * 256 + tid;        // 0..1023 over 8 tokens x 128 pts
    int tl = idx >> 7;
    int pt = idx & 127;
    int t = t0 + tl;
    int b = t / SSn, s = t % SSn;
    int lvl = (pt >> 2) & 3;
    int st, Wt;
    if (s < 4096)      { st = 0;    Wt = 64; }
    else if (s < 5120) { st = 4096; Wt = 32; }
    else if (s < 5376) { st = 5120; Wt = 16; }
    else               { st = 5376; Wt = 8;  }
    int p = s - st;
    int iy = p / Wt, ix = p % Wt;
    float refx = (ix + 0.5f) / Wt;
    float refy = (iy + 0.5f) / Wt;

    float logit = b2f(sa[(size_t)t * 384 + 256 + pt]);
    float m = logit;
    #pragma unroll
    for (int off = 1; off < 16; off <<= 1) m = fmaxf(m, __shfl_xor(m, off));
    float e = __expf(logit - m);
    float sum = e;
    #pragma unroll
    for (int off = 1; off < 16; off <<= 1) sum += __shfl_xor(sum, off);
    float wa = e / sum;

    const int LWt[4] = {64, 32, 16, 8};
    const int LST[4] = {0, 4096, 5120, 5376};
    int Wl = LWt[lvl], Hl = Wl, stl = LST[lvl];

    float ox = b2f(sa[(size_t)t * 384 + pt * 2]);
    float oy = b2f(sa[(size_t)t * 384 + pt * 2 + 1]);
    float x = refx * Wl + ox - 0.5f;
    float y = refy * Hl + oy - 0.5f;
    float x0f = floorf(x), y0f = floorf(y);
    int x0 = (int)x0f, y0 = (int)y0f;
    float wx1 = x - x0f, wy1 = y - y0f;
    int vbase = b * SSn + stl;
    int4 idx4; float4 w4;
    int* ip = (int*)&idx4; float* wp = (float*)&w4;
    #pragma unroll
    for (int c = 0; c < 4; ++c) {
      int dx = c & 1, dy = c >> 1;
      int xi = x0 + dx, yi = y0 + dy;
      float wgt = (dx ? wx1 : 1.f - wx1) * (dy ? wy1 : 1.f - wy1);
      bool valid = (xi >= 0) & (xi < Wl) & (yi >= 0) & (yi < Hl);
      int xc = min(max(xi, 0), Wl - 1), yc = min(max(yi, 0), Hl - 1);
      ip[c] = vbase + yc * Wl + xc;
      wp[c] = valid ? wgt * wa : 0.f;
    }
    int pi = pt + (pt >> 4);         // = h*17 + k
    sIdx4[tl][pi] = idx4;
    sW4[tl][pi] = w4;
  }
  __syncthreads();

  int tl = tid >> 5, v = tid & 31;
  int t = t0 + tl;
  int h = v >> 2, j = v & 3;
  int c0 = h * 32 + j * 8;           // 8 channels, 16B aligned
  float a0=0.f,a1=0.f,a2=0.f,a3=0.f,a4=0.f,a5=0.f,a6=0.f,a7=0.f;
  #pragma unroll
  for (int k = 0; k < 16; ++k) {
    int pi = h * 17 + k;
    int4 idx4 = sIdx4[tl][pi];
    float4 w4 = sW4[tl][pi];
    const int* ip = (const int*)&idx4;
    const float* wp = (const float*)&w4;
    #pragma unroll
    for (int c = 0; c < 4; ++c) {
      uint4 uv = *(const uint4*)(val + ((size_t)ip[c] << 8) + c0);
      float wv = wp[c];
      a0 += wv * __uint_as_float(uv.x << 16);
      a1 += wv * __uint_as_float(uv.x & 0xFFFF0000u);
      a2 += wv * __uint_as_float(uv.y << 16);
      a3 += wv * __uint_as_float(uv.y & 0xFFFF0000u);
      a4 += wv * __uint_as_float(uv.z << 16);
      a5 += wv * __uint_as_float(uv.z & 0xFFFF0000u);
      a6 += wv * __uint_as_float(uv.w << 16);
      a7 += wv * __uint_as_float(uv.w & 0xFFFF0000u);
    }
  }
  uint4 pk;
  pk.x = (uint32_t)f2b(a0) | ((uint32_t)f2b(a1) << 16);
  pk.y = (uint32_t)f2b(a2) | ((uint32_t)f2b(a3) << 16);
  pk.z = (uint32_t)f2b(a4) | ((uint32_t)f2b(a5) << 16);
  pk.w = (uint32_t)f2b(a6) | ((uint32_t)f2b(a7) << 16);
  *(uint4*)(att + (size_t)t * 256 + c0) = pk;
}

// ---------------------------------------------------------------------------
__global__ void tail_kernel(float* __restrict__ o) {
  const float v[12] = {64.f, 64.f, 32.f, 32.f, 16.f, 16.f, 8.f, 8.f,
                       0.f, 4096.f, 5120.f, 5376.f};
  int i = threadIdx.x;
  if (i < 12) o[i] = v[i];
}

// ---------------------------------------------------------------------------
extern "C" void kernel_launch(void* const* d_in, const int* in_sizes, int n_in,
                              void* d_out, int out_size, void* d_ws, size_t ws_size,
                              hipStream_t stream)
{
  const float* s0  = (const float*)d_in[0];
  const float* p0  = (const float*)d_in[1];
  const float* s1  = (const float*)d_in[2];
  const float* p1  = (const float*)d_in[3];
  const float* s2  = (const float*)d_in[4];
  const float* p2  = (const float*)d_in[5];
  const float* s3  = (const float*)d_in[6];
  const float* p3  = (const float*)d_in[7];
  const float* lev = (const float*)d_in[8];
  const float* W_so = (const float*)d_in[9];
  const float* b_so = (const float*)d_in[10];
  const float* W_aw = (const float*)d_in[11];
  const float* b_aw = (const float*)d_in[12];
  const float* W_v  = (const float*)d_in[13];
  const float* b_v  = (const float*)d_in[14];
  const float* W_o  = (const float*)d_in[15];
  const float* b_o  = (const float*)d_in[16];
  const float* g1   = (const float*)d_in[17];
  const float* be1  = (const float*)d_in[18];
  const float* W_f1 = (const float*)d_in[19];
  const float* b_f1 = (const float*)d_in[20];
  const float* W_f2 = (const float*)d_in[21];
  const float* b_f2 = (const float*)d_in[22];
  const float* g2   = (const float*)d_in[23];
  const float* be2  = (const float*)d_in[24];

  float* out = (float*)d_out;
  float* ws  = (float*)d_ws;

  // workspace layout (f32 units). Total ~5.41 TD = 120.5 MB.
  ushort_t* pos_b = (ushort_t*)ws;                          // 0.5 TD
  float*    x_f   = ws + TD / 2;                            // 1 TD
  ushort_t* q_b   = (ushort_t*)(ws + TD / 2 + TD);          // 0.5 TD (q / att)
  ushort_t* cur_b = (ushort_t*)(ws + 2 * TD);               // 0.5 TD
  ushort_t* x_b   = (ushort_t*)(ws + 2 * TD + TD / 2);      // 0.5 TD
  // H region: 2 TD. Phase1: sa_b (0.75 TD) + val_b (0.5 TD). Phase3: h_b (2 TD).
  ushort_t* sa_b  = (ushort_t*)(ws + 3 * TD);
  ushort_t* val_b = (ushort_t*)(ws + 3 * TD + 3 * (TD / 4));
  ushort_t* h_b   = (ushort_t*)(ws + 3 * TD);
  ushort_t* wt    = (ushort_t*)(ws + 5 * TD);               // 4,521,984 bf16
  float*    bsa   = ws + 5 * TD + 2260992;                  // 6*384 f32

  const size_t LW = 753664;  // per-layer transposed-weight stride (bf16)

  wprep_kernel<<<1104, 256, 0, stream>>>(W_so, W_aw, W_v, W_o, W_f1, W_f2, wt);
  bias_fuse<<<NL, 384, 0, stream>>>(b_so, b_aw, bsa);
  prep_kernel<<<1360, 256, 0, stream>>>(s0, p0, s1, p1, s2, p2, s3, p3, lev,
                                        out, cur_b, pos_b, q_b);

  for (int i = 0; i < NL; ++i) {
    ushort_t* wl = wt + (size_t)i * LW;
    const float* bv  = b_v  + (size_t)i * 256;
    const float* bo  = b_o  + (size_t)i * 256;
    const float* bf1 = b_f1 + (size_t)i * 1024;
    const float* bf2 = b_f2 + (size_t)i * 256;

    // merged: sa = q@Wsa (N=384) and val = cur@Wv (N=256)
    gemm_dual<<<dim3(170, 5), 256, 0, stream>>>(q_b, wl + 0, bsa + i * 384, sa_b,
                                                cur_b, wl + 98304, bv, val_b, 256);
    // deformable sampling -> att (bf16, overwrites q_b)
    sample_kernel<<<TTn / 8, 256, 0, stream>>>(val_b, sa_b, q_b);
    // Wo projection + residual(cur f32) + LN1 -> x_f, x_b
    gemm_ln<<<680, 256, 0, stream>>>(q_b, wl + 163840, bo, out,
                                     g1 + i * 256, be1 + i * 256,
                                     x_f, x_b, nullptr, nullptr, 256);
    // FFN1 (relu) -> h_b
    gemm_mfma<<<dim3(170, 8), 256, 0, stream>>>(x_b, wl + 229376, bf1,
                                                h_b, 1024, 256, 1);
    // FFN2 + residual(x_f) + LN2 -> out (f32), cur_b, q_b(next = y+pos)
    gemm_ln<<<680, 256, 0, stream>>>(h_b, wl + 491520, bf2, x_f,
                                     g2 + i * 256, be2 + i * 256,
                                     out, cur_b, q_b, pos_b, 1024);
  }

  tail_kernel<<<1, 16, 0, stream>>>(out + TD);
}

// Round 6
// 789.038 us; speedup vs baseline: 6.1363x; 1.0210x over previous
//
#include <hip/hip_runtime.h>
#include <cstdint>

#define SSn 5440
#define TTn 21760
#define TD ((size_t)TTn*256)
#define NL 6

typedef short bf16x8 __attribute__((ext_vector_type(8)));
typedef float f32x4 __attribute__((ext_vector_type(4)));
typedef float f32x2 __attribute__((ext_vector_type(2)));
typedef unsigned short u16x4 __attribute__((ext_vector_type(4)));
typedef unsigned short ushort_t;

__device__ __forceinline__ ushort_t f2b(float f) {
  uint32_t x = __float_as_uint(f);
  uint32_t r = x + 0x7FFFu + ((x >> 16) & 1u);
  return (ushort_t)(r >> 16);
}
__device__ __forceinline__ float b2f(ushort_t u) {
  return __uint_as_float((uint32_t)u << 16);
}

// ---------------------------------------------------------------------------
// Preprocess: tiled 64x64 LDS transpose. 340 tiles/batch x 4 = 1360 blocks.
__global__ __launch_bounds__(256) void prep_kernel(
    const float* __restrict__ s0, const float* __restrict__ p0,
    const float* __restrict__ s1, const float* __restrict__ p1,
    const float* __restrict__ s2, const float* __restrict__ p2,
    const float* __restrict__ s3, const float* __restrict__ p3,
    const float* __restrict__ lev,
    float* __restrict__ cur, ushort_t* __restrict__ cur_b,
    ushort_t* __restrict__ pos_b, ushort_t* __restrict__ q_b)
{
  __shared__ float ts[64][65];
  __shared__ float tp[64][65];
  int bx = blockIdx.x;
  int b = bx / 340, r = bx % 340;
  const float *sp, *pp; int l, HW, start, dt, ptile;
  if (r < 256)      { l=0; HW=4096; start=0;    sp=s0; pp=p0; dt=r>>6;       ptile=r&63; }
  else if (r < 320) { l=1; HW=1024; start=4096; sp=s1; pp=p1; dt=(r-256)>>4; ptile=(r-256)&15; }
  else if (r < 336) { l=2; HW=256;  start=5120; sp=s2; pp=p2; dt=(r-320)>>2; ptile=(r-320)&3; }
  else              { l=3; HW=64;   start=5376; sp=s3; pp=p3; dt=r-336;      ptile=0; }
  int d0 = dt * 64, pp0 = ptile * 64;
  int t = threadIdx.x;
  int rr = t >> 2, c4 = (t & 3) * 16;
  size_t ibase = ((size_t)b * 256 + d0 + rr) * HW + pp0;
  #pragma unroll
  for (int i = 0; i < 4; ++i) {
    f32x4 v = *(const f32x4*)(sp + ibase + c4 + i * 4);
    f32x4 w = *(const f32x4*)(pp + ibase + c4 + i * 4);
    #pragma unroll
    for (int j = 0; j < 4; ++j) { ts[c4 + i*4 + j][rr] = v[j]; tp[c4 + i*4 + j][rr] = w[j]; }
  }
  __syncthreads();
  int token = start + pp0 + rr;
  size_t obase = ((size_t)b * SSn + token) * 256 + d0;
  #pragma unroll
  for (int i = 0; i < 4; ++i) {
    f32x4 cv; u16x4 cb, pb, qb;
    #pragma unroll
    for (int j = 0; j < 4; ++j) {
      float c = ts[rr][c4 + i*4 + j];
      float p = tp[rr][c4 + i*4 + j] + lev[l * 256 + d0 + c4 + i*4 + j];
      cv[j] = c; cb[j] = f2b(c); pb[j] = f2b(p); qb[j] = f2b(c + p);
    }
    *(f32x4*)(cur + obase + c4 + i*4) = cv;
    *(u16x4*)(cur_b + obase + c4 + i*4) = cb;
    *(u16x4*)(pos_b + obase + c4 + i*4) = pb;
    *(u16x4*)(q_b + obase + c4 + i*4) = qb;
  }
}

// ---------------------------------------------------------------------------
// Batched weight transpose+convert (unchanged)
__global__ __launch_bounds__(256) void wprep_kernel(
    const float* __restrict__ W_so, const float* __restrict__ W_aw,
    const float* __restrict__ W_v,  const float* __restrict__ W_o,
    const float* __restrict__ W_f1, const float* __restrict__ W_f2,
    ushort_t* __restrict__ wt)
{
  __shared__ float tile[64][65];
  int bx = blockIdx.x;
  int layer = bx / 184, r = bx % 184;
  int type, ti;
  if (r < 16)       { type = 0; ti = r; }
  else if (r < 24)  { type = 1; ti = r - 16; }
  else if (r < 40)  { type = 2; ti = r - 24; }
  else if (r < 56)  { type = 3; ti = r - 40; }
  else if (r < 120) { type = 4; ti = r - 56; }
  else              { type = 5; ti = r - 120; }
  const float* src;
  int K, N, dof;
  switch (type) {
    case 0: src = W_so + (size_t)layer * 65536;  K = 256;  N = 256;  dof = 0;      break;
    case 1: src = W_aw + (size_t)layer * 32768;  K = 256;  N = 128;  dof = 65536;  break;
    case 2: src = W_v  + (size_t)layer * 65536;  K = 256;  N = 256;  dof = 98304;  break;
    case 3: src = W_o  + (size_t)layer * 65536;  K = 256;  N = 256;  dof = 163840; break;
    case 4: src = W_f1 + (size_t)layer * 262144; K = 256;  N = 1024; dof = 229376; break;
    default:src = W_f2 + (size_t)layer * 262144; K = 1024; N = 256;  dof = 491520; break;
  }
  int Kt = K >> 6;
  int k0 = (ti % Kt) * 64, n0 = (ti / Kt) * 64;
  ushort_t* dst = wt + (size_t)layer * 753664 + dof;
  int t = threadIdx.x;
  int rr = t >> 2, c4 = (t & 3) * 16;
  #pragma unroll
  for (int i = 0; i < 4; ++i) {
    f32x4 v = *(const f32x4*)(src + (size_t)(k0 + rr) * N + n0 + c4 + i * 4);
    tile[c4 + i*4 + 0][rr] = v[0];
    tile[c4 + i*4 + 1][rr] = v[1];
    tile[c4 + i*4 + 2][rr] = v[2];
    tile[c4 + i*4 + 3][rr] = v[3];
  }
  __syncthreads();
  #pragma unroll
  for (int i = 0; i < 4; ++i) {
    u16x4 o;
    #pragma unroll
    for (int j = 0; j < 4; ++j) o[j] = f2b(tile[rr][c4 + i*4 + j]);
    *(u16x4*)(dst + (size_t)(n0 + rr) * K + k0 + c4 + i * 4) = o;
  }
}

__global__ void bias_fuse(const float* __restrict__ bso,
                          const float* __restrict__ baw,
                          float* __restrict__ bsa)
{
  int l = blockIdx.x, t = threadIdx.x;
  bsa[l * 384 + t] = (t < 256) ? bso[l * 256 + t] : baw[l * 128 + t - 256];
}

// ---------------------------------------------------------------------------
// Shared 128x128 MFMA GEMM body (BK=64, 4 waves, swizzled LDS).
__device__ __forceinline__ void gemm_body(
    ushort_t* As, ushort_t* Bs,
    const ushort_t* __restrict__ A, const ushort_t* __restrict__ Bt,
    const float* __restrict__ bias, ushort_t* __restrict__ Cb,
    int N, int n0, int m0, int K, int relu)
{
  int t = threadIdx.x;
  int l = t & 63, w = t >> 6;
  int wr = w >> 1, wc = w & 1;
  int lq = l >> 4, l15 = l & 15, r7 = l & 7;
  f32x4 acc[4][4] = {};

  for (int k0 = 0; k0 < K; k0 += 64) {
    #pragma unroll
    for (int i = 0; i < 4; ++i) {
      int c = i * 256 + t;
      int row = c >> 3;
      int sc = (c & 7) ^ (row & 7);
      __builtin_amdgcn_global_load_lds(
          (const uint32_t*)(A + (size_t)(m0 + row) * K + k0 + sc * 8),
          (uint32_t*)((char*)As + c * 16), 16, 0, 0);
      __builtin_amdgcn_global_load_lds(
          (const uint32_t*)(Bt + (size_t)(n0 + row) * K + k0 + sc * 8),
          (uint32_t*)((char*)Bs + c * 16), 16, 0, 0);
    }
    __syncthreads();
    #pragma unroll
    for (int ks = 0; ks < 2; ++ks) {
      bf16x8 af[4], bfr[4];
      int chs = ((ks << 2) + lq) ^ r7;
      #pragma unroll
      for (int mt = 0; mt < 4; ++mt)
        af[mt] = *(const bf16x8*)((const char*)As +
                   (wr * 64 + mt * 16 + l15) * 128 + (chs << 4));
      #pragma unroll
      for (int nt = 0; nt < 4; ++nt)
        bfr[nt] = *(const bf16x8*)((const char*)Bs +
                   (wc * 64 + nt * 16 + l15) * 128 + (chs << 4));
      #pragma unroll
      for (int mt = 0; mt < 4; ++mt)
        #pragma unroll
        for (int nt = 0; nt < 4; ++nt)
          acc[mt][nt] = __builtin_amdgcn_mfma_f32_16x16x32_bf16(
              af[mt], bfr[nt], acc[mt][nt], 0, 0, 0);
    }
    __syncthreads();
  }

  int crow0 = m0 + wr * 64;
  int ccol0 = n0 + wc * 64;
  #pragma unroll
  for (int mt = 0; mt < 4; ++mt) {
    #pragma unroll
    for (int nt = 0; nt < 4; ++nt) {
      int col = ccol0 + nt * 16 + l15;
      float bv = bias[col];
      #pragma unroll
      for (int r = 0; r < 4; ++r) {
        int rowg = crow0 + mt * 16 + lq * 4 + r;
        float v = acc[mt][nt][r] + bv;
        if (relu) v = fmaxf(v, 0.f);
        Cb[(size_t)rowg * N + col] = f2b(v);
      }
    }
  }
}

// FFN1 GEMM (relu)
__global__ __launch_bounds__(256) void gemm_mfma(
    const ushort_t* __restrict__ A, const ushort_t* __restrict__ Bt,
    const float* __restrict__ bias, ushort_t* __restrict__ Cb,
    int N, int K, int relu)
{
  __shared__ alignas(16) ushort_t As[8192];
  __shared__ alignas(16) ushort_t Bs[8192];
  gemm_body(As, Bs, A, Bt, bias, Cb, N, blockIdx.y * 128, blockIdx.x * 128, K, relu);
}

// Merged sa(q@Wsa, N=384) + val(cur@Wv, N=256) dispatch: grid.y = 0..4
__global__ __launch_bounds__(256) void gemm_dual(
    const ushort_t* __restrict__ A0, const ushort_t* __restrict__ Bt0,
    const float* __restrict__ bias0, ushort_t* __restrict__ C0,
    const ushort_t* __restrict__ A1, const ushort_t* __restrict__ Bt1,
    const float* __restrict__ bias1, ushort_t* __restrict__ C1,
    int K)
{
  __shared__ alignas(16) ushort_t As[8192];
  __shared__ alignas(16) ushort_t Bs[8192];
  int gy = blockIdx.y;
  if (gy < 3)
    gemm_body(As, Bs, A0, Bt0, bias0, C0, 384, gy * 128, blockIdx.x * 128, K, 0);
  else
    gemm_body(As, Bs, A1, Bt1, bias1, C1, 256, (gy - 3) * 128, blockIdx.x * 128, K, 0);
}

// ---------------------------------------------------------------------------
// Fused GEMM (N=256) + residual + LayerNorm. Tile 32x256, 4 waves (256 thr).
__global__ __launch_bounds__(256) void gemm_ln(
    const ushort_t* __restrict__ A, const ushort_t* __restrict__ Bt,
    const float* __restrict__ bias, const float* __restrict__ res,
    const float* __restrict__ g, const float* __restrict__ be,
    float* __restrict__ Of, ushort_t* __restrict__ Ob,
    ushort_t* __restrict__ Oq, const ushort_t* __restrict__ posb,
    int K)
{
  __shared__ alignas(16) ushort_t As[32 * 64];    // 4 KB
  __shared__ alignas(16) ushort_t Bs[256 * 64];   // 32 KB
  __shared__ float psum[32][4];
  __shared__ float psum2[32][4];
  __shared__ float2 mstd[32];
  int t = threadIdx.x;
  int l = t & 63, w = t >> 6;          // w = column-span 0..3
  int m0 = blockIdx.x * 32;
  int lq = l >> 4, l15 = l & 15, r7 = l & 7;
  f32x4 acc[2][4] = {};

  for (int k0 = 0; k0 < K; k0 += 64) {
    {                                       // A: 256 chunks, 1/thread
      int c = t;
      int row = c >> 3;
      int sc = (c & 7) ^ (row & 7);
      __builtin_amdgcn_global_load_lds(
          (const uint32_t*)(A + (size_t)(m0 + row) * K + k0 + sc * 8),
          (uint32_t*)((char*)As + c * 16), 16, 0, 0);
    }
    #pragma unroll
    for (int i = 0; i < 8; ++i) {           // B: 2048 chunks
      int c = i * 256 + t;
      int row = c >> 3;
      int sc = (c & 7) ^ (row & 7);
      __builtin_amdgcn_global_load_lds(
          (const uint32_t*)(Bt + (size_t)row * K + k0 + sc * 8),
          (uint32_t*)((char*)Bs + c * 16), 16, 0, 0);
    }
    __syncthreads();
    #pragma unroll
    for (int ks = 0; ks < 2; ++ks) {
      bf16x8 af[2], bfr[4];
      int chs = ((ks << 2) + lq) ^ r7;
      #pragma unroll
      for (int mt = 0; mt < 2; ++mt)
        af[mt] = *(const bf16x8*)((const char*)As +
                   (mt * 16 + l15) * 128 + (chs << 4));
      #pragma unroll
      for (int nt = 0; nt < 4; ++nt)
        bfr[nt] = *(const bf16x8*)((const char*)Bs +
                   (w * 64 + nt * 16 + l15) * 128 + (chs << 4));
      #pragma unroll
      for (int mt = 0; mt < 2; ++mt)
        #pragma unroll
        for (int nt = 0; nt < 4; ++nt)
          acc[mt][nt] = __builtin_amdgcn_mfma_f32_16x16x32_bf16(
              af[mt], bfr[nt], acc[mt][nt], 0, 0, 0);
    }
    __syncthreads();
  }

  // epilogue: bias + residual, LN over 256-wide rows
  float gv[4], bev[4], biasv[4];
  #pragma unroll
  for (int nt = 0; nt < 4; ++nt) {
    int col = w * 64 + nt * 16 + l15;
    gv[nt] = g[col]; bev[nt] = be[col]; biasv[nt] = bias[col];
  }
  #pragma unroll
  for (int mt = 0; mt < 2; ++mt) {
    #pragma unroll
    for (int r = 0; r < 4; ++r) {
      int rowg = m0 + mt * 16 + lq * 4 + r;
      #pragma unroll
      for (int nt = 0; nt < 4; ++nt) {
        int col = w * 64 + nt * 16 + l15;
        acc[mt][nt][r] += biasv[nt] + res[(size_t)rowg * 256 + col];
      }
    }
  }
  #pragma unroll
  for (int mt = 0; mt < 2; ++mt) {
    #pragma unroll
    for (int r = 0; r < 4; ++r) {
      float s = 0.f, s2 = 0.f;
      #pragma unroll
      for (int nt = 0; nt < 4; ++nt) {
        float v = acc[mt][nt][r];
        s += v; s2 += v * v;
      }
      #pragma unroll
      for (int off = 1; off < 16; off <<= 1) {
        s  += __shfl_xor(s, off);
        s2 += __shfl_xor(s2, off);
      }
      if (l15 == 0) {
        int rloc = mt * 16 + lq * 4 + r;
        psum[rloc][w] = s;
        psum2[rloc][w] = s2;
      }
    }
  }
  __syncthreads();
  if (t < 32) {
    f32x4 a = *(const f32x4*)psum[t];
    f32x4 b = *(const f32x4*)psum2[t];
    float s = a[0] + a[1] + a[2] + a[3];
    float s2 = b[0] + b[1] + b[2] + b[3];
    float mean = s * (1.f / 256.f);
    float var = s2 * (1.f / 256.f) - mean * mean;
    mstd[t] = make_float2(mean, rsqrtf(var + 1e-5f));
  }
  __syncthreads();
  #pragma unroll
  for (int mt = 0; mt < 2; ++mt) {
    #pragma unroll
    for (int r = 0; r < 4; ++r) {
      int rloc = mt * 16 + lq * 4 + r;
      int rowg = m0 + rloc;
      float2 ms = mstd[rloc];
      #pragma unroll
      for (int nt = 0; nt < 4; ++nt) {
        int col = w * 64 + nt * 16 + l15;
        float y = (acc[mt][nt][r] - ms.x) * ms.y * gv[nt] + bev[nt];
        size_t o = (size_t)rowg * 256 + col;
        Of[o] = y;
        Ob[o] = f2b(y);
        if (Oq) Oq[o] = f2b(y + b2f(posb[o]));
      }
    }
  }
}

// ---------------------------------------------------------------------------
// Deformable sampling v6: 8 tokens/block, 32 thr/token, 8 channels/thread.
// ushort token-indices (26.1 KB LDS -> 6 blocks/CU) + packed f32x2 FMA.
__global__ __launch_bounds__(256) void sample_kernel(
    const ushort_t* __restrict__ val, const ushort_t* __restrict__ sa,
    ushort_t* __restrict__ att)
{
  __shared__ ushort4 sIdxU[8][136];
  __shared__ float4  sW4[8][136];
  int tid = threadIdx.x;
  int t0 = blockIdx.x * 8;

  #pragma unroll
  for (int it = 0; it < 4; ++it) {
    int idx = it * 256 + tid;        // 0..1023 over 8 tokens x 128 pts
    int tl = idx >> 7;
    int pt = idx & 127;
    int t = t0 + tl;
    int b = t / SSn, s = t % SSn;
    int lvl = (pt >> 2) & 3;
    int st, Wt;
    if (s < 4096)      { st = 0;    Wt = 64; }
    else if (s < 5120) { st = 4096; Wt = 32; }
    else if (s < 5376) { st = 5120; Wt = 16; }
    else               { st = 5376; Wt = 8;  }
    int p = s - st;
    int iy = p / Wt, ix = p % Wt;
    float refx = (ix + 0.5f) / Wt;
    float refy = (iy + 0.5f) / Wt;

    float logit = b2f(sa[(size_t)t * 384 + 256 + pt]);
    float m = logit;
    #pragma unroll
    for (int off = 1; off < 16; off <<= 1) m = fmaxf(m, __shfl_xor(m, off));
    float e = __expf(logit - m);
    float sum = e;
    #pragma unroll
    for (int off = 1; off < 16; off <<= 1) sum += __shfl_xor(sum, off);
    float wa = e / sum;

    const int LWt[4] = {64, 32, 16, 8};
    const int LST[4] = {0, 4096, 5120, 5376};
    int Wl = LWt[lvl], Hl = Wl, stl = LST[lvl];

    float ox = b2f(sa[(size_t)t * 384 + pt * 2]);
    float oy = b2f(sa[(size_t)t * 384 + pt * 2 + 1]);
    float x = refx * Wl + ox - 0.5f;
    float y = refy * Hl + oy - 0.5f;
    float x0f = floorf(x), y0f = floorf(y);
    int x0 = (int)x0f, y0 = (int)y0f;
    float wx1 = x - x0f, wy1 = y - y0f;
    int vbase = b * SSn + stl;
    ushort4 idxu; float4 w4;
    float* wp = (float*)&w4;
    unsigned short* ip = (unsigned short*)&idxu;
    #pragma unroll
    for (int c = 0; c < 4; ++c) {
      int dx = c & 1, dy = c >> 1;
      int xi = x0 + dx, yi = y0 + dy;
      float wgt = (dx ? wx1 : 1.f - wx1) * (dy ? wy1 : 1.f - wy1);
      bool valid = (xi >= 0) & (xi < Wl) & (yi >= 0) & (yi < Hl);
      int xc = min(max(xi, 0), Wl - 1), yc = min(max(yi, 0), Hl - 1);
      ip[c] = (unsigned short)(vbase + yc * Wl + xc);
      wp[c] = valid ? wgt * wa : 0.f;
    }
    int pi = pt + (pt >> 4);         // = h*17 + k
    sIdxU[tl][pi] = idxu;
    sW4[tl][pi] = w4;
  }
  __syncthreads();

  int tl = tid >> 5, v = tid & 31;
  int t = t0 + tl;
  int h = v >> 2, j = v & 3;
  int c0 = h * 32 + j * 8;           // 8 channels, 16B aligned
  f32x2 ac[4] = {};
  #pragma unroll
  for (int k = 0; k < 16; ++k) {
    int pi = h * 17 + k;
    ushort4 idxu = sIdxU[tl][pi];
    float4 w4 = sW4[tl][pi];
    const unsigned short* ip = (const unsigned short*)&idxu;
    const float* wp = (const float*)&w4;
    #pragma unroll
    for (int c = 0; c < 4; ++c) {
      uint4 uv = *(const uint4*)(val + ((size_t)ip[c] << 8) + c0);
      float wv = wp[c];
      f32x2 w2 = {wv, wv};
      f32x2 p0 = {__uint_as_float(uv.x << 16), __uint_as_float(uv.x & 0xFFFF0000u)};
      f32x2 p1 = {__uint_as_float(uv.y << 16), __uint_as_float(uv.y & 0xFFFF0000u)};
      f32x2 p2 = {__uint_as_float(uv.z << 16), __uint_as_float(uv.z & 0xFFFF0000u)};
      f32x2 p3 = {__uint_as_float(uv.w << 16), __uint_as_float(uv.w & 0xFFFF0000u)};
      ac[0] += w2 * p0;
      ac[1] += w2 * p1;
      ac[2] += w2 * p2;
      ac[3] += w2 * p3;
    }
  }
  uint4 pk;
  pk.x = (uint32_t)f2b(ac[0][0]) | ((uint32_t)f2b(ac[0][1]) << 16);
  pk.y = (uint32_t)f2b(ac[1][0]) | ((uint32_t)f2b(ac[1][1]) << 16);
  pk.z = (uint32_t)f2b(ac[2][0]) | ((uint32_t)f2b(ac[2][1]) << 16);
  pk.w = (uint32_t)f2b(ac[3][0]) | ((uint32_t)f2b(ac[3][1]) << 16);
  *(uint4*)(att + (size_t)t * 256 + c0) = pk;
}

// ---------------------------------------------------------------------------
__global__ void tail_kernel(float* __restrict__ o) {
  const float v[12] = {64.f, 64.f, 32.f, 32.f, 16.f, 16.f, 8.f, 8.f,
                       0.f, 4096.f, 5120.f, 5376.f};
  int i = threadIdx.x;
  if (i < 12) o[i] = v[i];
}

// ---------------------------------------------------------------------------
extern "C" void kernel_launch(void* const* d_in, const int* in_sizes, int n_in,
                              void* d_out, int out_size, void* d_ws, size_t ws_size,
                              hipStream_t stream)
{
  const float* s0  = (const float*)d_in[0];
  const float* p0  = (const float*)d_in[1];
  const float* s1  = (const float*)d_in[2];
  const float* p1  = (const float*)d_in[3];
  const float* s2  = (const float*)d_in[4];
  const float* p2  = (const float*)d_in[5];
  const float* s3  = (const float*)d_in[6];
  const float* p3  = (const float*)d_in[7];
  const float* lev = (const float*)d_in[8];
  const float* W_so = (const float*)d_in[9];
  const float* b_so = (const float*)d_in[10];
  const float* W_aw = (const float*)d_in[11];
  const float* b_aw = (const float*)d_in[12];
  const float* W_v  = (const float*)d_in[13];
  const float* b_v  = (const float*)d_in[14];
  const float* W_o  = (const float*)d_in[15];
  const float* b_o  = (const float*)d_in[16];
  const float* g1   = (const float*)d_in[17];
  const float* be1  = (const float*)d_in[18];
  const float* W_f1 = (const float*)d_in[19];
  const float* b_f1 = (const float*)d_in[20];
  const float* W_f2 = (const float*)d_in[21];
  const float* b_f2 = (const float*)d_in[22];
  const float* g2   = (const float*)d_in[23];
  const float* be2  = (const float*)d_in[24];

  float* out = (float*)d_out;
  float* ws  = (float*)d_ws;

  // workspace layout (f32 units). Total ~5.41 TD = 120.5 MB.
  ushort_t* pos_b = (ushort_t*)ws;                          // 0.5 TD
  float*    x_f   = ws + TD / 2;                            // 1 TD
  ushort_t* q_b   = (ushort_t*)(ws + TD / 2 + TD);          // 0.5 TD (q / att)
  ushort_t* cur_b = (ushort_t*)(ws + 2 * TD);               // 0.5 TD
  ushort_t* x_b   = (ushort_t*)(ws + 2 * TD + TD / 2);      // 0.5 TD
  // H region: 2 TD. Phase1: sa_b (0.75 TD) + val_b (0.5 TD). Phase3: h_b (2 TD).
  ushort_t* sa_b  = (ushort_t*)(ws + 3 * TD);
  ushort_t* val_b = (ushort_t*)(ws + 3 * TD + 3 * (TD / 4));
  ushort_t* h_b   = (ushort_t*)(ws + 3 * TD);
  ushort_t* wt    = (ushort_t*)(ws + 5 * TD);               // 4,521,984 bf16
  float*    bsa   = ws + 5 * TD + 2260992;                  // 6*384 f32

  const size_t LW = 753664;  // per-layer transposed-weight stride (bf16)

  wprep_kernel<<<1104, 256, 0, stream>>>(W_so, W_aw, W_v, W_o, W_f1, W_f2, wt);
  bias_fuse<<<NL, 384, 0, stream>>>(b_so, b_aw, bsa);
  prep_kernel<<<1360, 256, 0, stream>>>(s0, p0, s1, p1, s2, p2, s3, p3, lev,
                                        out, cur_b, pos_b, q_b);

  for (int i = 0; i < NL; ++i) {
    ushort_t* wl = wt + (size_t)i * LW;
    const float* bv  = b_v  + (size_t)i * 256;
    const float* bo  = b_o  + (size_t)i * 256;
    const float* bf1 = b_f1 + (size_t)i * 1024;
    const float* bf2 = b_f2 + (size_t)i * 256;

    // merged: sa = q@Wsa (N=384) and val = cur@Wv (N=256)
    gemm_dual<<<dim3(170, 5), 256, 0, stream>>>(q_b, wl + 0, bsa + i * 384, sa_b,
                                                cur_b, wl + 98304, bv, val_b, 256);
    // deformable sampling -> att (bf16, overwrites q_b)
    sample_kernel<<<TTn / 8, 256, 0, stream>>>(val_b, sa_b, q_b);
    // Wo projection + residual(cur f32) + LN1 -> x_f, x_b
    gemm_ln<<<680, 256, 0, stream>>>(q_b, wl + 163840, bo, out,
                                     g1 + i * 256, be1 + i * 256,
                                     x_f, x_b, nullptr, nullptr, 256);
    // FFN1 (relu) -> h_b
    gemm_mfma<<<dim3(170, 8), 256, 0, stream>>>(x_b, wl + 229376, bf1,
                                                h_b, 1024, 256, 1);
    // FFN2 + residual(x_f) + LN2 -> out (f32), cur_b, q_b(next = y+pos)
    gemm_ln<<<680, 256, 0, stream>>>(h_b, wl + 491520, bf2, x_f,
                                     g2 + i * 256, be2 + i * 256,
                                     out, cur_b, q_b, pos_b, 1024);
  }

  tail_kernel<<<1, 16, 0, stream>>>(out + TD);
}